// Round 9
// baseline (614.049 us; speedup 1.0000x reference)
//
#include <hip/hip_runtime.h>

// Conditional-DETR decoder layer, MI355X gfx950.
// R15 green @ 613.3 us. Dbuf+syncthreads was ~flat on CA kv (54->53): the
// end-of-iter __syncthreads drains vmcnt(0), killing the prefetch (in-flight
// window = compute phase only). Classic m97 barrier-drain stall.
// R16 (this): T4 counted-vmcnt + raw s_barrier in gemm_bb/gemm_sk_bb/
// attn_scores (canonical 2-buffer 2-deep schedule):
//   STAGE(0)->b0, STAGE(1)->b1; loop: vmcnt(4); bar; compute b[t&1]; bar;
//   STAGE(t+2)->b[t&1]; epilogue vmcnt(0). Loads stay in flight ACROSS
//   barriers (never drain to 0 mid-loop). attn_pv_sk unchanged (blast radius).
// Hazards: reads gated by own-vmcnt(4)+bar (all waves' stage-t landed);
// re-write of a buffer gated by second bar (all reads consumed). absmax must
// stay exactly 0.03125 (doubles as race screen).
// Predict: CA kv 53->~40 (Mfma ->27%), SA proj/CA q/scores/FFN similar;
// total 613 -> ~525-555.

typedef __bf16 bf16;
typedef __attribute__((ext_vector_type(8))) __bf16 bf16x8;
typedef __attribute__((ext_vector_type(4))) float f32x4;

#define D_MODEL 768
#define NH 6
#define HD 128
#define ROWSTRIDE (8 * D_MODEL)  // 6144 (B*D)

#define FENCE() asm volatile("" ::: "memory")

// XCD-aware chunked swizzle: requires gridDim.x*y*z % 8 == 0 (all our grids).
__device__ inline void swz_xyz(int& x, int& y, int& z) {
    const int nx = gridDim.x, ny = gridDim.y;
    const int n = nx * ny * gridDim.z;
    const int flat = blockIdx.x + nx * (blockIdx.y + ny * blockIdx.z);
    const int t = (flat & 7) * (n >> 3) + (flat >> 3);
    x = t % nx;
    const int r = t / nx;
    y = r % ny;
    z = r / ny;
}

// global->LDS direct DMA, 16 B per lane. Dest is wave-uniform base + lane*16.
__device__ __forceinline__ void gld16(const bf16* g, bf16* l) {
    __builtin_amdgcn_global_load_lds(
        (const __attribute__((address_space(1))) unsigned int*)g,
        (__attribute__((address_space(3))) unsigned int*)l, 16, 0, 0);
}

// 8-elem staging loaders -> bf16x8
__device__ inline bf16x8 ld8f(const float* p) {
    f32x4 a = *(const f32x4*)p, b = *(const f32x4*)(p + 4);
    bf16x8 r;
#pragma unroll
    for (int i = 0; i < 4; i++) { r[i] = (bf16)a[i]; r[i + 4] = (bf16)b[i]; }
    return r;
}
__device__ inline bf16x8 ld8bf(const bf16* p, const float* q) {  // bf16 + f32
    bf16x8 x = *(const bf16x8*)p;
    f32x4 a = *(const f32x4*)q, b = *(const f32x4*)(q + 4);
    bf16x8 r;
#pragma unroll
    for (int i = 0; i < 4; i++) { r[i] = (bf16)((float)x[i] + a[i]); r[i + 4] = (bf16)((float)x[i + 4] + b[i]); }
    return r;
}
__device__ inline bf16x8 ld8ff(const float* p, const float* q) {  // f32 + f32
    f32x4 a = *(const f32x4*)p, b = *(const f32x4*)(p + 4);
    f32x4 c = *(const f32x4*)q, d = *(const f32x4*)(q + 4);
    bf16x8 r;
#pragma unroll
    for (int i = 0; i < 4; i++) { r[i] = (bf16)(a[i] + c[i]); r[i + 4] = (bf16)(b[i] + d[i]); }
    return r;
}

// ---------------------------------------------------------------------------
// Multi-segment conversion (grid-stride; blockIdx.y = job).
struct CvtJob { const float* src; const float* src2; const bf16* add; bf16* dst; int nvec; };
struct CvtJobs { CvtJob j[12]; };

__global__ __launch_bounds__(256) void cvt_multi(CvtJobs jobs)
{
    const CvtJob jb = jobs.j[blockIdx.y];
    const int stride = gridDim.x * 256;
    if (jb.src2) {
        for (int i = blockIdx.x * 256 + threadIdx.x; i < jb.nvec; i += stride)
            *(bf16x8*)(jb.dst + (size_t)i * 8) = ld8ff(jb.src + (size_t)i * 8, jb.src2 + (size_t)i * 8);
    } else if (jb.add) {
        for (int i = blockIdx.x * 256 + threadIdx.x; i < jb.nvec; i += stride)
            *(bf16x8*)(jb.dst + (size_t)i * 8) = ld8bf(jb.add + (size_t)i * 8, jb.src + (size_t)i * 8);
    } else {
        for (int i = blockIdx.x * 256 + threadIdx.x; i < jb.nvec; i += stride)
            *(bf16x8*)(jb.dst + (size_t)i * 8) = ld8f(jb.src + (size_t)i * 8);
    }
}

// ---------------------------------------------------------------------------
// All-bf16 multi-job GEMM, gload_lds staging, counted-vmcnt 2-deep pipeline.
struct JobB { const bf16* A; const bf16* W; const float* bias; bf16* C; int relu; };
struct JobsB { JobB j[5]; };

__global__ __launch_bounds__(256) void gemm_bb(
    JobsB jobs, int lda, int ldw, int ldc, int K)
{
    __shared__ __align__(16) bf16 As[2][128 * 32];
    __shared__ __align__(16) bf16 Bs[2][128 * 32];
    int bx, by, bz;
    swz_xyz(bx, by, bz);
    const JobB jb = jobs.j[bz];
    const int bm = by * 128, bn = bx * 128;
    const int tid = threadIdx.x;
    const int wave = tid >> 6, lane = tid & 63;
    const int wm = (wave >> 1) * 64, wn = (wave & 1) * 64;
    const int quad = lane >> 4, m16 = lane & 15;
    const int crow = lane >> 2, ccol = (lane & 3) * 8;
    const bf16* a0 = jb.A + (size_t)(bm + wave * 32 + crow) * lda + ccol;
    const bf16* a1 = a0 + (size_t)16 * lda;
    const bf16* w0 = jb.W + (size_t)(bn + wave * 32 + crow) * ldw + ccol;
    const bf16* w1 = w0 + (size_t)16 * ldw;
    const int wo = wave * 1024;
    f32x4 acc[4][4] = {};
    auto stage = [&](int buf, int k) {
        bf16* dA = As[buf] + wo;
        bf16* dB = Bs[buf] + wo;
        gld16(a0 + k, dA);
        gld16(a1 + k, dA + 512);
        gld16(w0 + k, dB);
        gld16(w1 + k, dB + 512);
    };
    auto compute = [&](int buf) {
        const bf16* rA = As[buf];
        const bf16* rB = Bs[buf];
        bf16x8 af[4], bfr[4];
#pragma unroll
        for (int i = 0; i < 4; i++) {
            af[i]  = *(const bf16x8*)&rA[(wm + i * 16 + m16) * 32 + quad * 8];
            bfr[i] = *(const bf16x8*)&rB[(wn + i * 16 + m16) * 32 + quad * 8];
        }
#pragma unroll
        for (int i = 0; i < 4; i++)
#pragma unroll
            for (int j = 0; j < 4; j++)
                acc[i][j] = __builtin_amdgcn_mfma_f32_16x16x32_bf16(af[i], bfr[j], acc[i][j], 0, 0, 0);
    };
    stage(0, 0);
    stage(1, 32);
    int cur = 0;
    for (int k0 = 0; k0 < K - 32; k0 += 32) {
        asm volatile("s_waitcnt vmcnt(4)" ::: "memory");
        __builtin_amdgcn_s_barrier();
        FENCE();
        compute(cur);
        FENCE();
        __builtin_amdgcn_s_barrier();
        FENCE();
        const int kp2 = k0 + 64;
        if (kp2 < K) stage(cur, kp2);
        cur ^= 1;
    }
    asm volatile("s_waitcnt vmcnt(0)" ::: "memory");
    __builtin_amdgcn_s_barrier();
    FENCE();
    compute(cur);
#pragma unroll
    for (int j = 0; j < 4; j++) {
        const int col = bn + wn + j * 16 + m16;
        const float bv = jb.bias[col];
#pragma unroll
        for (int i = 0; i < 4; i++)
#pragma unroll
            for (int r = 0; r < 4; r++) {
                const int row = bm + wm + i * 16 + quad * 4 + r;
                float val = acc[i][j][r] + bv;
                if (jb.relu) val = fmaxf(val, 0.f);
                jb.C[(size_t)row * ldc + col] = (bf16)val;
            }
    }
}

// ---------------------------------------------------------------------------
// All-bf16 split-K GEMM, counted-vmcnt pipeline, fp32 partials.
__global__ __launch_bounds__(256) void gemm_sk_bb(
    const bf16* __restrict__ A, int lda, const bf16* __restrict__ W, int ldw,
    float* __restrict__ Cp, size_t cstride, int ldc, int Ks)
{
    __shared__ __align__(16) bf16 As[2][128 * 32];
    __shared__ __align__(16) bf16 Bs[2][128 * 32];
    int bx, by, bz;
    swz_xyz(bx, by, bz);
    const int bm = by * 128, bn = bx * 128;
    const int kbase = bz * Ks;
    const int tid = threadIdx.x;
    const int wave = tid >> 6, lane = tid & 63;
    const int wm = (wave >> 1) * 64, wn = (wave & 1) * 64;
    const int quad = lane >> 4, m16 = lane & 15;
    const int crow = lane >> 2, ccol = (lane & 3) * 8;
    const bf16* a0 = A + (size_t)(bm + wave * 32 + crow) * lda + kbase + ccol;
    const bf16* a1 = a0 + (size_t)16 * lda;
    const bf16* w0 = W + (size_t)(bn + wave * 32 + crow) * ldw + kbase + ccol;
    const bf16* w1 = w0 + (size_t)16 * ldw;
    const int wo = wave * 1024;
    f32x4 acc[4][4] = {};
    auto stage = [&](int buf, int k) {
        bf16* dA = As[buf] + wo;
        bf16* dB = Bs[buf] + wo;
        gld16(a0 + k, dA);
        gld16(a1 + k, dA + 512);
        gld16(w0 + k, dB);
        gld16(w1 + k, dB + 512);
    };
    auto compute = [&](int buf) {
        const bf16* rA = As[buf];
        const bf16* rB = Bs[buf];
        bf16x8 af[4], bfr[4];
#pragma unroll
        for (int i = 0; i < 4; i++) {
            af[i]  = *(const bf16x8*)&rA[(wm + i * 16 + m16) * 32 + quad * 8];
            bfr[i] = *(const bf16x8*)&rB[(wn + i * 16 + m16) * 32 + quad * 8];
        }
#pragma unroll
        for (int i = 0; i < 4; i++)
#pragma unroll
            for (int j = 0; j < 4; j++)
                acc[i][j] = __builtin_amdgcn_mfma_f32_16x16x32_bf16(af[i], bfr[j], acc[i][j], 0, 0, 0);
    };
    stage(0, 0);
    stage(1, 32);
    int cur = 0;
    for (int k0 = 0; k0 < Ks - 32; k0 += 32) {
        asm volatile("s_waitcnt vmcnt(4)" ::: "memory");
        __builtin_amdgcn_s_barrier();
        FENCE();
        compute(cur);
        FENCE();
        __builtin_amdgcn_s_barrier();
        FENCE();
        const int kp2 = k0 + 64;
        if (kp2 < Ks) stage(cur, kp2);
        cur ^= 1;
    }
    asm volatile("s_waitcnt vmcnt(0)" ::: "memory");
    __builtin_amdgcn_s_barrier();
    FENCE();
    compute(cur);
    float* out = Cp + (size_t)bz * cstride;
#pragma unroll
    for (int j = 0; j < 4; j++) {
        const int col = bn + wn + j * 16 + m16;
#pragma unroll
        for (int i = 0; i < 4; i++)
#pragma unroll
            for (int r = 0; r < 4; r++) {
                const int row = bm + wm + i * 16 + quad * 4 + r;
                out[(size_t)row * ldc + col] = acc[i][j][r];
            }
    }
}

// ---------------------------------------------------------------------------
// scores[bh,l,s] = scale*(qc.kc + qp.kp), K=256. Counted-vmcnt pipeline.
__global__ __launch_bounds__(256) void attn_scores(
    const bf16* __restrict__ qc, const bf16* __restrict__ qp,
    const bf16* __restrict__ kc, const bf16* __restrict__ kp,
    bf16* __restrict__ scores, int Lq, int S, float scale)
{
    __shared__ __align__(16) bf16 As[2][128 * 32];
    __shared__ __align__(16) bf16 Bs[2][128 * 32];
    int bx, by, bz;
    swz_xyz(bx, by, bz);
    const int bh = bz;
    const int b = bh / NH, h = bh % NH;
    const int bm = by * 128, bn = bx * 128;
    const int tid = threadIdx.x;
    const int wave = tid >> 6, lane = tid & 63;
    const int wm = (wave >> 1) * 64, wn = (wave & 1) * 64;
    const int quad = lane >> 4, m16 = lane & 15;
    const int crow = lane >> 2, ccol = (lane & 3) * 8;
    const size_t hb = (size_t)b * D_MODEL + h * HD;
    const size_t ar0 = (size_t)(bm + wave * 32 + crow) * ROWSTRIDE + hb + ccol;
    const size_t ar1 = ar0 + (size_t)16 * ROWSTRIDE;
    const size_t br0 = (size_t)(bn + wave * 32 + crow) * ROWSTRIDE + hb + ccol;
    const size_t br1 = br0 + (size_t)16 * ROWSTRIDE;
    const int wo = wave * 1024;
    f32x4 acc[4][4] = {};
    auto stage = [&](int buf, int k) {
        const bf16* qsrc = (k < 128) ? qc : qp;
        const bf16* ksrc = (k < 128) ? kc : kp;
        const int kcol = k & 127;
        bf16* dA = As[buf] + wo;
        bf16* dB = Bs[buf] + wo;
        gld16(qsrc + ar0 + kcol, dA);
        gld16(qsrc + ar1 + kcol, dA + 512);
        gld16(ksrc + br0 + kcol, dB);
        gld16(ksrc + br1 + kcol, dB + 512);
    };
    auto compute = [&](int buf) {
        const bf16* rA = As[buf];
        const bf16* rB = Bs[buf];
        bf16x8 af[4], bfr[4];
#pragma unroll
        for (int i = 0; i < 4; i++) {
            af[i]  = *(const bf16x8*)&rA[(wm + i * 16 + m16) * 32 + quad * 8];
            bfr[i] = *(const bf16x8*)&rB[(wn + i * 16 + m16) * 32 + quad * 8];
        }
#pragma unroll
        for (int i = 0; i < 4; i++)
#pragma unroll
            for (int j = 0; j < 4; j++)
                acc[i][j] = __builtin_amdgcn_mfma_f32_16x16x32_bf16(af[i], bfr[j], acc[i][j], 0, 0, 0);
    };
    stage(0, 0);
    stage(1, 32);
    int cur = 0;
    for (int k0 = 0; k0 < 224; k0 += 32) {
        asm volatile("s_waitcnt vmcnt(4)" ::: "memory");
        __builtin_amdgcn_s_barrier();
        FENCE();
        compute(cur);
        FENCE();
        __builtin_amdgcn_s_barrier();
        FENCE();
        const int kp2 = k0 + 64;
        if (kp2 < 256) stage(cur, kp2);
        cur ^= 1;
    }
    asm volatile("s_waitcnt vmcnt(0)" ::: "memory");
    __builtin_amdgcn_s_barrier();
    FENCE();
    compute(cur);
    bf16* sb = scores + (size_t)bh * Lq * S;
#pragma unroll
    for (int i = 0; i < 4; i++)
#pragma unroll
        for (int j = 0; j < 4; j++)
#pragma unroll
            for (int r = 0; r < 4; r++)
                sb[(size_t)(bm + wm + i * 16 + quad * 4 + r) * S + bn + wn + j * 16 + m16]
                    = (bf16)(acc[i][j][r] * scale);
}

// ---------------------------------------------------------------------------
// Fused softmax + head-mean. One block per (b,l): all NH=6 head rows.
template <int N>
__global__ __launch_bounds__(256) void softmax_mean(
    bf16* __restrict__ scores, float* __restrict__ att, int Lq)
{
    const int S = N << 8;
    const int l = blockIdx.x, b = blockIdx.y;
    const int tid = threadIdx.x;
    __shared__ float red[4], red2[4];
    float macc[N];
#pragma unroll
    for (int i = 0; i < N; i++) macc[i] = 0.f;
    for (int h = 0; h < NH; h++) {
        bf16* p = scores + ((size_t)(b * NH + h) * Lq + l) * S;
        float vals[N];
        float mx = -1e30f;
#pragma unroll
        for (int i = 0; i < N; i++) { vals[i] = (float)p[tid + (i << 8)]; mx = fmaxf(mx, vals[i]); }
        for (int off = 32; off; off >>= 1) mx = fmaxf(mx, __shfl_xor(mx, off, 64));
        if ((tid & 63) == 0) red[tid >> 6] = mx;
        __syncthreads();
        mx = fmaxf(fmaxf(red[0], red[1]), fmaxf(red[2], red[3]));
        float sum = 0.f;
#pragma unroll
        for (int i = 0; i < N; i++) { vals[i] = __expf(vals[i] - mx); sum += vals[i]; }
        for (int off = 32; off; off >>= 1) sum += __shfl_xor(sum, off, 64);
        if ((tid & 63) == 0) red2[tid >> 6] = sum;
        __syncthreads();
        const float inv = 1.f / (red2[0] + red2[1] + red2[2] + red2[3]);
#pragma unroll
        for (int i = 0; i < N; i++) {
            const float w = vals[i] * inv;
            p[tid + (i << 8)] = (bf16)w;
            macc[i] += w;
        }
    }
    float* ao = att + ((size_t)b * Lq + l) * S;
#pragma unroll
    for (int i = 0; i < N; i++) ao[tid + (i << 8)] = macc[i] * (1.f / 6.f);
}

// ---------------------------------------------------------------------------
// Split-S PV. A-side (softmax weights) via gload_lds; V transposed reg-scatter.
__global__ __launch_bounds__(256) void attn_pv_sk(
    const bf16* __restrict__ wsm, const bf16* __restrict__ v,
    float* __restrict__ Pv, size_t pstride, int Lq, int S)
{
    __shared__ __align__(16) bf16 As[128 * 32];
    __shared__ __align__(16) bf16 BsT[128][40];
    int bx, by, bz;
    swz_xyz(bx, by, bz);
    const int bh = bz;
    const int b = bh / NH, h = bh % NH;
    const int bm = bx * 128;
    const int kbase = by * (S >> 1);
    const int tid = threadIdx.x;
    const int wave = tid >> 6, lane = tid & 63;
    const int wm = (wave >> 1) * 64, wn = (wave & 1) * 64;
    const int quad = lane >> 4, m16 = lane & 15;
    const int crow = lane >> 2, ccol = (lane & 3) * 8;
    const int kk0 = tid >> 4, e0 = (tid & 15) * 8;
    f32x4 acc[4][4] = {};
    const bf16* wbase = wsm + (size_t)(bh * Lq + bm) * S + kbase;
    const size_t vb = (size_t)b * D_MODEL + h * HD;
    const bf16* a0 = wbase + (size_t)(wave * 32 + crow) * S + ccol;
    const bf16* a1 = a0 + (size_t)16 * S;
    bf16* lA = As + wave * 1024;
    bf16x8 v0, v1;
    v0 = *(const bf16x8*)(v + (size_t)(kbase + kk0) * ROWSTRIDE + vb + e0);
    v1 = *(const bf16x8*)(v + (size_t)(kbase + kk0 + 16) * ROWSTRIDE + vb + e0);
    for (int k0 = 0; k0 < (S >> 1); k0 += 32) {
        gld16(a0 + k0, lA);
        gld16(a1 + k0, lA + 512);
#pragma unroll
        for (int i = 0; i < 8; i++) { BsT[e0 + i][kk0] = v0[i]; BsT[e0 + i][kk0 + 16] = v1[i]; }
        __syncthreads();
        const int kn = k0 + 32;
        if (kn < (S >> 1)) {
            v0 = *(const bf16x8*)(v + (size_t)(kbase + kn + kk0) * ROWSTRIDE + vb + e0);
            v1 = *(const bf16x8*)(v + (size_t)(kbase + kn + kk0 + 16) * ROWSTRIDE + vb + e0);
        }
        bf16x8 af[4], bfr[4];
#pragma unroll
        for (int i = 0; i < 4; i++) {
            af[i]  = *(const bf16x8*)&As[(wm + i * 16 + m16) * 32 + quad * 8];
            bfr[i] = *(const bf16x8*)&BsT[wn + i * 16 + m16][quad * 8];
        }
#pragma unroll
        for (int i = 0; i < 4; i++)
#pragma unroll
            for (int j = 0; j < 4; j++)
                acc[i][j] = __builtin_amdgcn_mfma_f32_16x16x32_bf16(af[i], bfr[j], acc[i][j], 0, 0, 0);
        __syncthreads();
    }
    float* out = Pv + by * pstride;
#pragma unroll
    for (int i = 0; i < 4; i++)
#pragma unroll
        for (int j = 0; j < 4; j++)
#pragma unroll
            for (int r = 0; r < 4; r++)
                out[(size_t)(bm + wm + i * 16 + quad * 4 + r) * ROWSTRIDE + vb + wn + j * 16 + m16]
                    = acc[i][j][r];
}

// ---------------------------------------------------------------------------
// out = LN(resid + sum_{p<NP} P[p] + xbias) * g + be.
template <int NP, typename TR, typename TO>
__global__ __launch_bounds__(256) void add_ln_p(
    const TR* __restrict__ resid, const float* __restrict__ P, size_t pstride,
    const float* __restrict__ xbias,
    const float* __restrict__ g, const float* __restrict__ be, TO* __restrict__ out)
{
    const size_t base = (size_t)blockIdx.x * D_MODEL;
    const int tid = threadIdx.x;
    float v[3];
#pragma unroll
    for (int i = 0; i < 3; i++) {
        const int c = tid + (i << 8);
        float x = xbias[c];
#pragma unroll
        for (int p = 0; p < NP; p++) x += P[p * pstride + base + c];
        v[i] = (float)resid[base + c] + x;
    }
    float s = v[0] + v[1] + v[2];
    float s2 = v[0] * v[0] + v[1] * v[1] + v[2] * v[2];
    for (int off = 32; off; off >>= 1) { s += __shfl_xor(s, off, 64); s2 += __shfl_xor(s2, off, 64); }
    __shared__ float rs[4], rs2[4];
    if ((tid & 63) == 0) { rs[tid >> 6] = s; rs2[tid >> 6] = s2; }
    __syncthreads();
    s = rs[0] + rs[1] + rs[2] + rs[3];
    s2 = rs2[0] + rs2[1] + rs2[2] + rs2[3];
    const float mean = s * (1.f / 768.f);
    const float var = s2 * (1.f / 768.f) - mean * mean;
    const float inv = rsqrtf(var + 1e-5f);
#pragma unroll
    for (int i = 0; i < 3; i++) {
        const int c = tid + (i << 8);
        out[base + c] = (TO)((v[i] - mean) * inv * g[c] + be[c]);
    }
}

// ---------------------------------------------------------------------------
extern "C" void kernel_launch(void* const* d_in, const int* in_sizes, int n_in,
                              void* d_out, int out_size, void* d_ws, size_t ws_size,
                              hipStream_t stream)
{
    const float* tgt        = (const float*)d_in[0];
    const float* memory     = (const float*)d_in[1];
    const float* tgt_pos    = (const float*)d_in[2];
    const float* memory_pos = (const float*)d_in[3];
    const float* tgt_pos2   = (const float*)d_in[4];
    const float *sa_w[6], *sa_b[6], *ca_w[6], *ca_b[6];
    for (int i = 0; i < 6; i++) {
        sa_w[i] = (const float*)d_in[5 + 2 * i];  sa_b[i] = (const float*)d_in[6 + 2 * i];
        ca_w[i] = (const float*)d_in[17 + 2 * i]; ca_b[i] = (const float*)d_in[18 + 2 * i];
    }
    const float* ff1_w = (const float*)d_in[29]; const float* ff1_b = (const float*)d_in[30];
    const float* ff2_w = (const float*)d_in[31]; const float* ff2_b = (const float*)d_in[32];
    const float* ln_g[3] = {(const float*)d_in[33], (const float*)d_in[35], (const float*)d_in[37]};
    const float* ln_b[3] = {(const float*)d_in[34], (const float*)d_in[36], (const float*)d_in[38]};

    // ---- workspace (106,954,752 B) ----
    char* ws = (char*)d_ws;
    bf16* qc  = (bf16*)(ws);                // [0, 6291456)
    bf16* qp  = (bf16*)(ws + 6291456);      // [6291456, 12582912)
    bf16* kc  = (bf16*)(ws + 12582912);     // [12582912, 25165824)
    bf16* kp  = (bf16*)(ws + 25165824);     // [25165824, 37748736)
    bf16* vv  = (bf16*)(ws + 37748736);     // [37748736, 50331648)
    bf16* t1  = (bf16*)(ws + 50331648);     // [50331648, 56623104)
    bf16* sc  = (bf16*)(ws + 56623104);     // [56623104, 106954752) 50.33 MB
    const size_t PSTRIDE = 3145728;  // floats per 12.58 MB slice
    float* pv_sa = (float*)(ws + 81788928);  // sc_hi: SA PV pair (sc_lo = SA scores live)
    float* pv_ca = (float*)(ws + 12582912);  // kc+kp: dead after CA scores
    float* op    = (float*)(ws + 56623104);  // sc_lo: out-proj pair (both phases)
    float* fp    = (float*)(ws + 56623104);  // FFN2 4-slice = full sc (dead)
    bf16*  tca   = kc;                       // Pv_ca dead after CA out-proj
    bf16*  ffh   = kp;                       // 16.78 MB over dead kp+vv

    // bf16 staging (liveness-checked; see R14/R15 notes):
    bf16* tgt_b    = sc;
    bf16* mem_b    = sc;
    bf16* mempos_b = sc + 6291456;
    bf16* wb       = (bf16*)d_out;
    const size_t WSTEP = 589824;  // 768*768
    bf16* tp_b   = (bf16*)((char*)d_out + 12582912);
    bf16* qpin_b = tp_b + 3145728;
    bf16* ff1b   = qc;
    bf16* ff2b   = qp;
    bf16* savA   = kc;                      // 6.29 MB
    bf16* saw5b  = kc + 3145728;            // +1.18 MB
    bf16* cavA   = vv;                      // 6.29 MB
    bf16* caw5b  = vv + 3145728;            // +1.18 MB

    float* out_t    = (float*)d_out;        // (L,B,D)
    float* out_att  = out_t + 3145728;      // (B,L,S)
    float* out_satt = out_att + 4194304;    // (B,L,L)

    const dim3 blk(256);
    const float SCALE = 0.0625f;

    // ---- cvt pass 1: 10 weights + tgt + tgt_pos(persistent) ----
    {
        CvtJobs C = {};
        for (int i = 0; i < 5; i++) C.j[i] = {sa_w[i], nullptr, nullptr, wb + i * WSTEP, 73728};
        for (int i = 0; i < 3; i++) C.j[5 + i] = {ca_w[2 + i], nullptr, nullptr, wb + (5 + i) * WSTEP, 73728};
        C.j[8]  = {ca_w[0], nullptr, nullptr, wb + 8 * WSTEP, 73728};
        C.j[9]  = {ca_w[1], nullptr, nullptr, wb + 9 * WSTEP, 73728};
        C.j[10] = {tgt,     nullptr, nullptr, tgt_b, 393216};
        C.j[11] = {tgt_pos, nullptr, nullptr, tp_b,  393216};
        cvt_multi<<<dim3(288, 12), blk, 0, stream>>>(C);
    }

    // ---- self attention ----
    {
        JobsB J = {};
        J.j[0] = {tp_b,  wb + 0 * WSTEP, sa_b[0], qc, 0};
        J.j[1] = {tgt_b, wb + 1 * WSTEP, sa_b[1], qp, 0};
        J.j[2] = {tp_b,  wb + 2 * WSTEP, sa_b[2], kc, 0};
        J.j[3] = {tgt_b, wb + 3 * WSTEP, sa_b[3], kp, 0};
        J.j[4] = {tgt_b, wb + 4 * WSTEP, sa_b[4], vv, 0};
        gemm_bb<<<dim3(6, 32, 5), blk, 0, stream>>>(J, 768, 768, 768, 768);
    }
    attn_scores<<<dim3(4, 4, 48), blk, 0, stream>>>(qc, qp, kc, kp, sc, 512, 512, SCALE);
    softmax_mean<2><<<dim3(512, 8), blk, 0, stream>>>(sc, out_satt, 512);
    attn_pv_sk<<<dim3(4, 2, 48), blk, 0, stream>>>(sc, vv, pv_sa, PSTRIDE, 512, 512);
    // fuse: savA = bf16(pv0 + pv1); saw5b = bf16(sa_w[5])
    {
        CvtJobs C = {};
        C.j[0] = {pv_sa, pv_sa + PSTRIDE, nullptr, savA,  393216};
        C.j[1] = {sa_w[5], nullptr,       nullptr, saw5b, 73728};
        cvt_multi<<<dim3(288, 2), blk, 0, stream>>>(C);
    }
    gemm_sk_bb<<<dim3(6, 32, 2), blk, 0, stream>>>(savA, 768, saw5b, 768,
                                                   op, PSTRIDE, 768, 384);
    add_ln_p<2, float, bf16><<<dim3(4096), blk, 0, stream>>>(tgt, op, PSTRIDE, sa_b[5],
                                                             ln_g[0], ln_b[0], t1);

    // ---- cvt pass 2: memory, memory_pos, qp-input = bf16(t1 + tgt_pos2) ----
    {
        CvtJobs C = {};
        C.j[0] = {memory,     nullptr, nullptr, mem_b,    786432};
        C.j[1] = {memory_pos, nullptr, nullptr, mempos_b, 786432};
        C.j[2] = {tgt_pos2,   nullptr, t1,      qpin_b,   393216};
        cvt_multi<<<dim3(288, 3), blk, 0, stream>>>(C);
    }

    // ---- cross attention ----
    {
        JobsB J = {};
        J.j[0] = {tp_b,   wb + 8 * WSTEP, ca_b[0], qc, 0};
        J.j[1] = {qpin_b, wb + 9 * WSTEP, ca_b[1], qp, 0};
        gemm_bb<<<dim3(6, 32, 2), blk, 0, stream>>>(J, 768, 768, 768, 768);
    }
    {
        JobsB J = {};
        J.j[0] = {mem_b,    wb + 5 * WSTEP, ca_b[2], kc, 0};
        J.j[1] = {mempos_b, wb + 6 * WSTEP, ca_b[3], kp, 0};
        J.j[2] = {mempos_b, wb + 7 * WSTEP, ca_b[4], vv, 0};
        gemm_bb<<<dim3(6, 64, 3), blk, 0, stream>>>(J, 768, 768, 768, 768);
    }
    attn_scores<<<dim3(8, 4, 48), blk, 0, stream>>>(qc, qp, kc, kp, sc, 512, 1024, SCALE);
    // ---- cvt pass 3: FFN weights into dead qc/qp ----
    {
        CvtJobs C = {};
        C.j[0] = {ff1_w, nullptr, nullptr, ff1b, 196608};
        C.j[1] = {ff2_w, nullptr, nullptr, ff2b, 196608};
        cvt_multi<<<dim3(288, 2), blk, 0, stream>>>(C);
    }
    softmax_mean<4><<<dim3(512, 8), blk, 0, stream>>>(sc, out_att, 512);
    attn_pv_sk<<<dim3(4, 2, 48), blk, 0, stream>>>(sc, vv, pv_ca, PSTRIDE, 512, 1024);
    // fuse: cavA = bf16(pv0 + pv1); caw5b = bf16(ca_w[5])
    {
        CvtJobs C = {};
        C.j[0] = {pv_ca, pv_ca + PSTRIDE, nullptr, cavA,  393216};
        C.j[1] = {ca_w[5], nullptr,       nullptr, caw5b, 73728};
        cvt_multi<<<dim3(288, 2), blk, 0, stream>>>(C);
    }
    gemm_sk_bb<<<dim3(6, 32, 2), blk, 0, stream>>>(cavA, 768, caw5b, 768,
                                                   op, PSTRIDE, 768, 384);
    add_ln_p<2, bf16, bf16><<<dim3(4096), blk, 0, stream>>>(t1, op, PSTRIDE, ca_b[5],
                                                            ln_g[1], ln_b[1], tca);

    // ---- FFN ----
    {
        JobsB J = {};
        J.j[0] = {tca, ff1b, ff1_b, ffh, 1};
        gemm_bb<<<dim3(16, 32, 1), blk, 0, stream>>>(J, 768, 768, 2048, 768);
    }
    gemm_sk_bb<<<dim3(6, 32, 4), blk, 0, stream>>>(ffh, 2048, ff2b, 2048,
                                                   fp, PSTRIDE, 768, 512);
    add_ln_p<4, bf16, float><<<dim3(4096), blk, 0, stream>>>(tca, fp, PSTRIDE, ff2_b,
                                                             ln_g[2], ln_b[2], out_t);
}

// Round 10
// 608.569 us; speedup vs baseline: 1.0090x; 1.0090x over previous
//
#include <hip/hip_runtime.h>

// Conditional-DETR decoder layer, MI355X gfx950.
// R16 @ 614.0 us (null vs R15 613.3): counted-vmcnt didn't move CA kv (52.5us).
// CA kv = 552 TF = 91% of the 2-phase structural ceiling (m233: 607 TF) ->
// K-loop is done; remaining time is in occupancy-starved SMALL dispatches
// (CA q / outprojs / PV at 384 blocks = 1.5/CU, ~100-200 TF each).
// R17 (this): occupancy/fusion round, inner loops untouched:
//  1) gemm_multi: per-job y-extent decode -> CA q + CA kv fused into ONE
//     1536-block dispatch; SA proj + FFN1 use same kernel (same shapes).
//  2) outprojs split-K z=2->4 (Ks=192, 768 blocks); add_ln_p<4> sums 4 fp32
//     planes (4x12.58MB in dead sc at both sites, liveness checked).
// absmax may shift last-ulp (split-K fp32 regrouping) but stays ~0.03125.
// Predict: fused CA dispatch ~60-66us (vs 80 sum), outprojs ~23 each;
// total 614 -> ~575-590.

typedef __bf16 bf16;
typedef __attribute__((ext_vector_type(8))) __bf16 bf16x8;
typedef __attribute__((ext_vector_type(4))) float f32x4;

#define D_MODEL 768
#define NH 6
#define HD 128
#define ROWSTRIDE (8 * D_MODEL)  // 6144 (B*D)

#define FENCE() asm volatile("" ::: "memory")

// XCD-aware chunked swizzle: requires gridDim.x*y*z % 8 == 0 (all our grids).
__device__ inline void swz_xyz(int& x, int& y, int& z) {
    const int nx = gridDim.x, ny = gridDim.y;
    const int n = nx * ny * gridDim.z;
    const int flat = blockIdx.x + nx * (blockIdx.y + ny * blockIdx.z);
    const int t = (flat & 7) * (n >> 3) + (flat >> 3);
    x = t % nx;
    const int r = t / nx;
    y = r % ny;
    z = r / ny;
}

// global->LDS direct DMA, 16 B per lane. Dest is wave-uniform base + lane*16.
__device__ __forceinline__ void gld16(const bf16* g, bf16* l) {
    __builtin_amdgcn_global_load_lds(
        (const __attribute__((address_space(1))) unsigned int*)g,
        (__attribute__((address_space(3))) unsigned int*)l, 16, 0, 0);
}

// 8-elem staging loaders -> bf16x8
__device__ inline bf16x8 ld8f(const float* p) {
    f32x4 a = *(const f32x4*)p, b = *(const f32x4*)(p + 4);
    bf16x8 r;
#pragma unroll
    for (int i = 0; i < 4; i++) { r[i] = (bf16)a[i]; r[i + 4] = (bf16)b[i]; }
    return r;
}
__device__ inline bf16x8 ld8bf(const bf16* p, const float* q) {  // bf16 + f32
    bf16x8 x = *(const bf16x8*)p;
    f32x4 a = *(const f32x4*)q, b = *(const f32x4*)(q + 4);
    bf16x8 r;
#pragma unroll
    for (int i = 0; i < 4; i++) { r[i] = (bf16)((float)x[i] + a[i]); r[i + 4] = (bf16)((float)x[i + 4] + b[i]); }
    return r;
}
__device__ inline bf16x8 ld8ff(const float* p, const float* q) {  // f32 + f32
    f32x4 a = *(const f32x4*)p, b = *(const f32x4*)(p + 4);
    f32x4 c = *(const f32x4*)q, d = *(const f32x4*)(q + 4);
    bf16x8 r;
#pragma unroll
    for (int i = 0; i < 4; i++) { r[i] = (bf16)(a[i] + c[i]); r[i + 4] = (bf16)(b[i] + d[i]); }
    return r;
}

// ---------------------------------------------------------------------------
// Multi-segment conversion (grid-stride; blockIdx.y = job).
struct CvtJob { const float* src; const float* src2; const bf16* add; bf16* dst; int nvec; };
struct CvtJobs { CvtJob j[12]; };

__global__ __launch_bounds__(256) void cvt_multi(CvtJobs jobs)
{
    const CvtJob jb = jobs.j[blockIdx.y];
    const int stride = gridDim.x * 256;
    if (jb.src2) {
        for (int i = blockIdx.x * 256 + threadIdx.x; i < jb.nvec; i += stride)
            *(bf16x8*)(jb.dst + (size_t)i * 8) = ld8ff(jb.src + (size_t)i * 8, jb.src2 + (size_t)i * 8);
    } else if (jb.add) {
        for (int i = blockIdx.x * 256 + threadIdx.x; i < jb.nvec; i += stride)
            *(bf16x8*)(jb.dst + (size_t)i * 8) = ld8bf(jb.add + (size_t)i * 8, jb.src + (size_t)i * 8);
    } else {
        for (int i = blockIdx.x * 256 + threadIdx.x; i < jb.nvec; i += stride)
            *(bf16x8*)(jb.dst + (size_t)i * 8) = ld8f(jb.src + (size_t)i * 8);
    }
}

// ---------------------------------------------------------------------------
// All-bf16 multi-job GEMM with per-job y-extents (flat y decode), gload_lds
// staging, counted-vmcnt 2-deep pipeline. jobs.j[i].ycum = cumulative y-tiles.
struct JobM { const bf16* A; const bf16* W; const float* bias; bf16* C;
              int relu; int ycum; };
struct JobsM { JobM j[5]; };

__global__ __launch_bounds__(256) void gemm_multi(
    JobsM jobs, int lda, int ldw, int ldc, int K)
{
    __shared__ __align__(16) bf16 As[2][128 * 32];
    __shared__ __align__(16) bf16 Bs[2][128 * 32];
    int bx, byg, bzu;
    swz_xyz(bx, byg, bzu);
    int ji = 0;
    while (ji < 4 && byg >= jobs.j[ji].ycum) ji++;
    const JobM jb = jobs.j[ji];
    const int ybase = (ji == 0) ? 0 : jobs.j[ji - 1].ycum;
    const int bm = (byg - ybase) * 128, bn = bx * 128;
    const int tid = threadIdx.x;
    const int wave = tid >> 6, lane = tid & 63;
    const int wm = (wave >> 1) * 64, wn = (wave & 1) * 64;
    const int quad = lane >> 4, m16 = lane & 15;
    const int crow = lane >> 2, ccol = (lane & 3) * 8;
    const bf16* a0 = jb.A + (size_t)(bm + wave * 32 + crow) * lda + ccol;
    const bf16* a1 = a0 + (size_t)16 * lda;
    const bf16* w0 = jb.W + (size_t)(bn + wave * 32 + crow) * ldw + ccol;
    const bf16* w1 = w0 + (size_t)16 * ldw;
    const int wo = wave * 1024;
    f32x4 acc[4][4] = {};
    auto stage = [&](int buf, int k) {
        bf16* dA = As[buf] + wo;
        bf16* dB = Bs[buf] + wo;
        gld16(a0 + k, dA);
        gld16(a1 + k, dA + 512);
        gld16(w0 + k, dB);
        gld16(w1 + k, dB + 512);
    };
    auto compute = [&](int buf) {
        const bf16* rA = As[buf];
        const bf16* rB = Bs[buf];
        bf16x8 af[4], bfr[4];
#pragma unroll
        for (int i = 0; i < 4; i++) {
            af[i]  = *(const bf16x8*)&rA[(wm + i * 16 + m16) * 32 + quad * 8];
            bfr[i] = *(const bf16x8*)&rB[(wn + i * 16 + m16) * 32 + quad * 8];
        }
#pragma unroll
        for (int i = 0; i < 4; i++)
#pragma unroll
            for (int j = 0; j < 4; j++)
                acc[i][j] = __builtin_amdgcn_mfma_f32_16x16x32_bf16(af[i], bfr[j], acc[i][j], 0, 0, 0);
    };
    stage(0, 0);
    stage(1, 32);
    int cur = 0;
    for (int k0 = 0; k0 < K - 32; k0 += 32) {
        asm volatile("s_waitcnt vmcnt(4)" ::: "memory");
        __builtin_amdgcn_s_barrier();
        FENCE();
        compute(cur);
        FENCE();
        __builtin_amdgcn_s_barrier();
        FENCE();
        const int kp2 = k0 + 64;
        if (kp2 < K) stage(cur, kp2);
        cur ^= 1;
    }
    asm volatile("s_waitcnt vmcnt(0)" ::: "memory");
    __builtin_amdgcn_s_barrier();
    FENCE();
    compute(cur);
#pragma unroll
    for (int j = 0; j < 4; j++) {
        const int col = bn + wn + j * 16 + m16;
        const float bv = jb.bias[col];
#pragma unroll
        for (int i = 0; i < 4; i++)
#pragma unroll
            for (int r = 0; r < 4; r++) {
                const int row = bm + wm + i * 16 + quad * 4 + r;
                float val = acc[i][j][r] + bv;
                if (jb.relu) val = fmaxf(val, 0.f);
                jb.C[(size_t)row * ldc + col] = (bf16)val;
            }
    }
}

// ---------------------------------------------------------------------------
// All-bf16 split-K GEMM, counted-vmcnt pipeline, fp32 partials.
__global__ __launch_bounds__(256) void gemm_sk_bb(
    const bf16* __restrict__ A, int lda, const bf16* __restrict__ W, int ldw,
    float* __restrict__ Cp, size_t cstride, int ldc, int Ks)
{
    __shared__ __align__(16) bf16 As[2][128 * 32];
    __shared__ __align__(16) bf16 Bs[2][128 * 32];
    int bx, by, bz;
    swz_xyz(bx, by, bz);
    const int bm = by * 128, bn = bx * 128;
    const int kbase = bz * Ks;
    const int tid = threadIdx.x;
    const int wave = tid >> 6, lane = tid & 63;
    const int wm = (wave >> 1) * 64, wn = (wave & 1) * 64;
    const int quad = lane >> 4, m16 = lane & 15;
    const int crow = lane >> 2, ccol = (lane & 3) * 8;
    const bf16* a0 = A + (size_t)(bm + wave * 32 + crow) * lda + kbase + ccol;
    const bf16* a1 = a0 + (size_t)16 * lda;
    const bf16* w0 = W + (size_t)(bn + wave * 32 + crow) * ldw + kbase + ccol;
    const bf16* w1 = w0 + (size_t)16 * ldw;
    const int wo = wave * 1024;
    f32x4 acc[4][4] = {};
    auto stage = [&](int buf, int k) {
        bf16* dA = As[buf] + wo;
        bf16* dB = Bs[buf] + wo;
        gld16(a0 + k, dA);
        gld16(a1 + k, dA + 512);
        gld16(w0 + k, dB);
        gld16(w1 + k, dB + 512);
    };
    auto compute = [&](int buf) {
        const bf16* rA = As[buf];
        const bf16* rB = Bs[buf];
        bf16x8 af[4], bfr[4];
#pragma unroll
        for (int i = 0; i < 4; i++) {
            af[i]  = *(const bf16x8*)&rA[(wm + i * 16 + m16) * 32 + quad * 8];
            bfr[i] = *(const bf16x8*)&rB[(wn + i * 16 + m16) * 32 + quad * 8];
        }
#pragma unroll
        for (int i = 0; i < 4; i++)
#pragma unroll
            for (int j = 0; j < 4; j++)
                acc[i][j] = __builtin_amdgcn_mfma_f32_16x16x32_bf16(af[i], bfr[j], acc[i][j], 0, 0, 0);
    };
    stage(0, 0);
    stage(1, 32);
    int cur = 0;
    for (int k0 = 0; k0 < Ks - 32; k0 += 32) {
        asm volatile("s_waitcnt vmcnt(4)" ::: "memory");
        __builtin_amdgcn_s_barrier();
        FENCE();
        compute(cur);
        FENCE();
        __builtin_amdgcn_s_barrier();
        FENCE();
        const int kp2 = k0 + 64;
        if (kp2 < Ks) stage(cur, kp2);
        cur ^= 1;
    }
    asm volatile("s_waitcnt vmcnt(0)" ::: "memory");
    __builtin_amdgcn_s_barrier();
    FENCE();
    compute(cur);
    float* out = Cp + (size_t)bz * cstride;
#pragma unroll
    for (int j = 0; j < 4; j++) {
        const int col = bn + wn + j * 16 + m16;
#pragma unroll
        for (int i = 0; i < 4; i++)
#pragma unroll
            for (int r = 0; r < 4; r++) {
                const int row = bm + wm + i * 16 + quad * 4 + r;
                out[(size_t)row * ldc + col] = acc[i][j][r];
            }
    }
}

// ---------------------------------------------------------------------------
// scores[bh,l,s] = scale*(qc.kc + qp.kp), K=256. Counted-vmcnt pipeline.
__global__ __launch_bounds__(256) void attn_scores(
    const bf16* __restrict__ qc, const bf16* __restrict__ qp,
    const bf16* __restrict__ kc, const bf16* __restrict__ kp,
    bf16* __restrict__ scores, int Lq, int S, float scale)
{
    __shared__ __align__(16) bf16 As[2][128 * 32];
    __shared__ __align__(16) bf16 Bs[2][128 * 32];
    int bx, by, bz;
    swz_xyz(bx, by, bz);
    const int bh = bz;
    const int b = bh / NH, h = bh % NH;
    const int bm = by * 128, bn = bx * 128;
    const int tid = threadIdx.x;
    const int wave = tid >> 6, lane = tid & 63;
    const int wm = (wave >> 1) * 64, wn = (wave & 1) * 64;
    const int quad = lane >> 4, m16 = lane & 15;
    const int crow = lane >> 2, ccol = (lane & 3) * 8;
    const size_t hb = (size_t)b * D_MODEL + h * HD;
    const size_t ar0 = (size_t)(bm + wave * 32 + crow) * ROWSTRIDE + hb + ccol;
    const size_t ar1 = ar0 + (size_t)16 * ROWSTRIDE;
    const size_t br0 = (size_t)(bn + wave * 32 + crow) * ROWSTRIDE + hb + ccol;
    const size_t br1 = br0 + (size_t)16 * ROWSTRIDE;
    const int wo = wave * 1024;
    f32x4 acc[4][4] = {};
    auto stage = [&](int buf, int k) {
        const bf16* qsrc = (k < 128) ? qc : qp;
        const bf16* ksrc = (k < 128) ? kc : kp;
        const int kcol = k & 127;
        bf16* dA = As[buf] + wo;
        bf16* dB = Bs[buf] + wo;
        gld16(qsrc + ar0 + kcol, dA);
        gld16(qsrc + ar1 + kcol, dA + 512);
        gld16(ksrc + br0 + kcol, dB);
        gld16(ksrc + br1 + kcol, dB + 512);
    };
    auto compute = [&](int buf) {
        const bf16* rA = As[buf];
        const bf16* rB = Bs[buf];
        bf16x8 af[4], bfr[4];
#pragma unroll
        for (int i = 0; i < 4; i++) {
            af[i]  = *(const bf16x8*)&rA[(wm + i * 16 + m16) * 32 + quad * 8];
            bfr[i] = *(const bf16x8*)&rB[(wn + i * 16 + m16) * 32 + quad * 8];
        }
#pragma unroll
        for (int i = 0; i < 4; i++)
#pragma unroll
            for (int j = 0; j < 4; j++)
                acc[i][j] = __builtin_amdgcn_mfma_f32_16x16x32_bf16(af[i], bfr[j], acc[i][j], 0, 0, 0);
    };
    stage(0, 0);
    stage(1, 32);
    int cur = 0;
    for (int k0 = 0; k0 < 224; k0 += 32) {
        asm volatile("s_waitcnt vmcnt(4)" ::: "memory");
        __builtin_amdgcn_s_barrier();
        FENCE();
        compute(cur);
        FENCE();
        __builtin_amdgcn_s_barrier();
        FENCE();
        const int kp2 = k0 + 64;
        if (kp2 < 256) stage(cur, kp2);
        cur ^= 1;
    }
    asm volatile("s_waitcnt vmcnt(0)" ::: "memory");
    __builtin_amdgcn_s_barrier();
    FENCE();
    compute(cur);
    bf16* sb = scores + (size_t)bh * Lq * S;
#pragma unroll
    for (int i = 0; i < 4; i++)
#pragma unroll
        for (int j = 0; j < 4; j++)
#pragma unroll
            for (int r = 0; r < 4; r++)
                sb[(size_t)(bm + wm + i * 16 + quad * 4 + r) * S + bn + wn + j * 16 + m16]
                    = (bf16)(acc[i][j][r] * scale);
}

// ---------------------------------------------------------------------------
// Fused softmax + head-mean. One block per (b,l): all NH=6 head rows.
template <int N>
__global__ __launch_bounds__(256) void softmax_mean(
    bf16* __restrict__ scores, float* __restrict__ att, int Lq)
{
    const int S = N << 8;
    const int l = blockIdx.x, b = blockIdx.y;
    const int tid = threadIdx.x;
    __shared__ float red[4], red2[4];
    float macc[N];
#pragma unroll
    for (int i = 0; i < N; i++) macc[i] = 0.f;
    for (int h = 0; h < NH; h++) {
        bf16* p = scores + ((size_t)(b * NH + h) * Lq + l) * S;
        float vals[N];
        float mx = -1e30f;
#pragma unroll
        for (int i = 0; i < N; i++) { vals[i] = (float)p[tid + (i << 8)]; mx = fmaxf(mx, vals[i]); }
        for (int off = 32; off; off >>= 1) mx = fmaxf(mx, __shfl_xor(mx, off, 64));
        if ((tid & 63) == 0) red[tid >> 6] = mx;
        __syncthreads();
        mx = fmaxf(fmaxf(red[0], red[1]), fmaxf(red[2], red[3]));
        float sum = 0.f;
#pragma unroll
        for (int i = 0; i < N; i++) { vals[i] = __expf(vals[i] - mx); sum += vals[i]; }
        for (int off = 32; off; off >>= 1) sum += __shfl_xor(sum, off, 64);
        if ((tid & 63) == 0) red2[tid >> 6] = sum;
        __syncthreads();
        const float inv = 1.f / (red2[0] + red2[1] + red2[2] + red2[3]);
#pragma unroll
        for (int i = 0; i < N; i++) {
            const float w = vals[i] * inv;
            p[tid + (i << 8)] = (bf16)w;
            macc[i] += w;
        }
    }
    float* ao = att + ((size_t)b * Lq + l) * S;
#pragma unroll
    for (int i = 0; i < N; i++) ao[tid + (i << 8)] = macc[i] * (1.f / 6.f);
}

// ---------------------------------------------------------------------------
// Split-S PV. A-side (softmax weights) via gload_lds; V transposed reg-scatter.
__global__ __launch_bounds__(256) void attn_pv_sk(
    const bf16* __restrict__ wsm, const bf16* __restrict__ v,
    float* __restrict__ Pv, size_t pstride, int Lq, int S)
{
    __shared__ __align__(16) bf16 As[128 * 32];
    __shared__ __align__(16) bf16 BsT[128][40];
    int bx, by, bz;
    swz_xyz(bx, by, bz);
    const int bh = bz;
    const int b = bh / NH, h = bh % NH;
    const int bm = bx * 128;
    const int kbase = by * (S >> 1);
    const int tid = threadIdx.x;
    const int wave = tid >> 6, lane = tid & 63;
    const int wm = (wave >> 1) * 64, wn = (wave & 1) * 64;
    const int quad = lane >> 4, m16 = lane & 15;
    const int crow = lane >> 2, ccol = (lane & 3) * 8;
    const int kk0 = tid >> 4, e0 = (tid & 15) * 8;
    f32x4 acc[4][4] = {};
    const bf16* wbase = wsm + (size_t)(bh * Lq + bm) * S + kbase;
    const size_t vb = (size_t)b * D_MODEL + h * HD;
    const bf16* a0 = wbase + (size_t)(wave * 32 + crow) * S + ccol;
    const bf16* a1 = a0 + (size_t)16 * S;
    bf16* lA = As + wave * 1024;
    bf16x8 v0, v1;
    v0 = *(const bf16x8*)(v + (size_t)(kbase + kk0) * ROWSTRIDE + vb + e0);
    v1 = *(const bf16x8*)(v + (size_t)(kbase + kk0 + 16) * ROWSTRIDE + vb + e0);
    for (int k0 = 0; k0 < (S >> 1); k0 += 32) {
        gld16(a0 + k0, lA);
        gld16(a1 + k0, lA + 512);
#pragma unroll
        for (int i = 0; i < 8; i++) { BsT[e0 + i][kk0] = v0[i]; BsT[e0 + i][kk0 + 16] = v1[i]; }
        __syncthreads();
        const int kn = k0 + 32;
        if (kn < (S >> 1)) {
            v0 = *(const bf16x8*)(v + (size_t)(kbase + kn + kk0) * ROWSTRIDE + vb + e0);
            v1 = *(const bf16x8*)(v + (size_t)(kbase + kn + kk0 + 16) * ROWSTRIDE + vb + e0);
        }
        bf16x8 af[4], bfr[4];
#pragma unroll
        for (int i = 0; i < 4; i++) {
            af[i]  = *(const bf16x8*)&As[(wm + i * 16 + m16) * 32 + quad * 8];
            bfr[i] = *(const bf16x8*)&BsT[wn + i * 16 + m16][quad * 8];
        }
#pragma unroll
        for (int i = 0; i < 4; i++)
#pragma unroll
            for (int j = 0; j < 4; j++)
                acc[i][j] = __builtin_amdgcn_mfma_f32_16x16x32_bf16(af[i], bfr[j], acc[i][j], 0, 0, 0);
        __syncthreads();
    }
    float* out = Pv + by * pstride;
#pragma unroll
    for (int i = 0; i < 4; i++)
#pragma unroll
        for (int j = 0; j < 4; j++)
#pragma unroll
            for (int r = 0; r < 4; r++)
                out[(size_t)(bm + wm + i * 16 + quad * 4 + r) * ROWSTRIDE + vb + wn + j * 16 + m16]
                    = acc[i][j][r];
}

// ---------------------------------------------------------------------------
// out = LN(resid + sum_{p<NP} P[p] + xbias) * g + be.
template <int NP, typename TR, typename TO>
__global__ __launch_bounds__(256) void add_ln_p(
    const TR* __restrict__ resid, const float* __restrict__ P, size_t pstride,
    const float* __restrict__ xbias,
    const float* __restrict__ g, const float* __restrict__ be, TO* __restrict__ out)
{
    const size_t base = (size_t)blockIdx.x * D_MODEL;
    const int tid = threadIdx.x;
    float v[3];
#pragma unroll
    for (int i = 0; i < 3; i++) {
        const int c = tid + (i << 8);
        float x = xbias[c];
#pragma unroll
        for (int p = 0; p < NP; p++) x += P[p * pstride + base + c];
        v[i] = (float)resid[base + c] + x;
    }
    float s = v[0] + v[1] + v[2];
    float s2 = v[0] * v[0] + v[1] * v[1] + v[2] * v[2];
    for (int off = 32; off; off >>= 1) { s += __shfl_xor(s, off, 64); s2 += __shfl_xor(s2, off, 64); }
    __shared__ float rs[4], rs2[4];
    if ((tid & 63) == 0) { rs[tid >> 6] = s; rs2[tid >> 6] = s2; }
    __syncthreads();
    s = rs[0] + rs[1] + rs[2] + rs[3];
    s2 = rs2[0] + rs2[1] + rs2[2] + rs2[3];
    const float mean = s * (1.f / 768.f);
    const float var = s2 * (1.f / 768.f) - mean * mean;
    const float inv = rsqrtf(var + 1e-5f);
#pragma unroll
    for (int i = 0; i < 3; i++) {
        const int c = tid + (i << 8);
        out[base + c] = (TO)((v[i] - mean) * inv * g[c] + be[c]);
    }
}

// ---------------------------------------------------------------------------
extern "C" void kernel_launch(void* const* d_in, const int* in_sizes, int n_in,
                              void* d_out, int out_size, void* d_ws, size_t ws_size,
                              hipStream_t stream)
{
    const float* tgt        = (const float*)d_in[0];
    const float* memory     = (const float*)d_in[1];
    const float* tgt_pos    = (const float*)d_in[2];
    const float* memory_pos = (const float*)d_in[3];
    const float* tgt_pos2   = (const float*)d_in[4];
    const float *sa_w[6], *sa_b[6], *ca_w[6], *ca_b[6];
    for (int i = 0; i < 6; i++) {
        sa_w[i] = (const float*)d_in[5 + 2 * i];  sa_b[i] = (const float*)d_in[6 + 2 * i];
        ca_w[i] = (const float*)d_in[17 + 2 * i]; ca_b[i] = (const float*)d_in[18 + 2 * i];
    }
    const float* ff1_w = (const float*)d_in[29]; const float* ff1_b = (const float*)d_in[30];
    const float* ff2_w = (const float*)d_in[31]; const float* ff2_b = (const float*)d_in[32];
    const float* ln_g[3] = {(const float*)d_in[33], (const float*)d_in[35], (const float*)d_in[37]};
    const float* ln_b[3] = {(const float*)d_in[34], (const float*)d_in[36], (const float*)d_in[38]};

    // ---- workspace (106,954,752 B) ----
    char* ws = (char*)d_ws;
    bf16* qc  = (bf16*)(ws);                // [0, 6291456)
    bf16* qp  = (bf16*)(ws + 6291456);      // [6291456, 12582912)
    bf16* kc  = (bf16*)(ws + 12582912);     // [12582912, 25165824)
    bf16* kp  = (bf16*)(ws + 25165824);     // [25165824, 37748736)
    bf16* vv  = (bf16*)(ws + 37748736);     // [37748736, 50331648)
    bf16* t1  = (bf16*)(ws + 50331648);     // [50331648, 56623104)
    bf16* sc  = (bf16*)(ws + 56623104);     // [56623104, 106954752) 50.33 MB
    const size_t PSTRIDE = 3145728;  // floats per 12.58 MB slice
    float* pv_sa = (float*)(ws + 81788928);  // sc_hi: SA PV pair (sc_lo = SA scores live)
    float* pv_ca = (float*)(ws + 12582912);  // kc+kp: dead after CA scores
    float* op    = (float*)(ws + 56623104);  // 4 K-slices = full sc (dead at outproj time)
    float* fp    = (float*)(ws + 56623104);  // FFN2 4-slice = full sc (dead)
    bf16*  tca   = kc;                       // Pv_ca dead after CA out-proj
    bf16*  ffh   = kp;                       // 16.78 MB over dead kp+vv

    // bf16 staging (liveness-checked; see R14/R15 notes):
    bf16* tgt_b    = sc;
    bf16* mem_b    = sc;
    bf16* mempos_b = sc + 6291456;
    bf16* wb       = (bf16*)d_out;
    const size_t WSTEP = 589824;  // 768*768
    bf16* tp_b   = (bf16*)((char*)d_out + 12582912);
    bf16* qpin_b = tp_b + 3145728;
    bf16* ff1b   = qc;
    bf16* ff2b   = qp;
    bf16* savA   = kc;                      // 6.29 MB
    bf16* saw5b  = kc + 3145728;            // +1.18 MB
    bf16* cavA   = vv;                      // 6.29 MB
    bf16* caw5b  = vv + 3145728;            // +1.18 MB

    float* out_t    = (float*)d_out;        // (L,B,D)
    float* out_att  = out_t + 3145728;      // (B,L,S)
    float* out_satt = out_att + 4194304;    // (B,L,L)

    const dim3 blk(256);
    const float SCALE = 0.0625f;
    const int BIG = 0x7fffffff;

    // ---- cvt pass 1: 10 weights + tgt + tgt_pos(persistent) ----
    {
        CvtJobs C = {};
        for (int i = 0; i < 5; i++) C.j[i] = {sa_w[i], nullptr, nullptr, wb + i * WSTEP, 73728};
        for (int i = 0; i < 3; i++) C.j[5 + i] = {ca_w[2 + i], nullptr, nullptr, wb + (5 + i) * WSTEP, 73728};
        C.j[8]  = {ca_w[0], nullptr, nullptr, wb + 8 * WSTEP, 73728};
        C.j[9]  = {ca_w[1], nullptr, nullptr, wb + 9 * WSTEP, 73728};
        C.j[10] = {tgt,     nullptr, nullptr, tgt_b, 393216};
        C.j[11] = {tgt_pos, nullptr, nullptr, tp_b,  393216};
        cvt_multi<<<dim3(288, 12), blk, 0, stream>>>(C);
    }

    // ---- self attention: 5 projections, one dispatch (960 blocks) ----
    {
        JobsM J = {};
        J.j[0] = {tp_b,  wb + 0 * WSTEP, sa_b[0], qc, 0, 32};
        J.j[1] = {tgt_b, wb + 1 * WSTEP, sa_b[1], qp, 0, 64};
        J.j[2] = {tp_b,  wb + 2 * WSTEP, sa_b[2], kc, 0, 96};
        J.j[3] = {tgt_b, wb + 3 * WSTEP, sa_b[3], kp, 0, 128};
        J.j[4] = {tgt_b, wb + 4 * WSTEP, sa_b[4], vv, 0, 160};
        gemm_multi<<<dim3(6, 160), blk, 0, stream>>>(J, 768, 768, 768, 768);
    }
    attn_scores<<<dim3(4, 4, 48), blk, 0, stream>>>(qc, qp, kc, kp, sc, 512, 512, SCALE);
    softmax_mean<2><<<dim3(512, 8), blk, 0, stream>>>(sc, out_satt, 512);
    attn_pv_sk<<<dim3(4, 2, 48), blk, 0, stream>>>(sc, vv, pv_sa, PSTRIDE, 512, 512);
    // fuse: savA = bf16(pv0 + pv1); saw5b = bf16(sa_w[5])
    {
        CvtJobs C = {};
        C.j[0] = {pv_sa, pv_sa + PSTRIDE, nullptr, savA,  393216};
        C.j[1] = {sa_w[5], nullptr,       nullptr, saw5b, 73728};
        cvt_multi<<<dim3(288, 2), blk, 0, stream>>>(C);
    }
    // SA out-proj: split-K z=4 (Ks=192), 768 blocks; 4 fp32 planes in sc.
    gemm_sk_bb<<<dim3(6, 32, 4), blk, 0, stream>>>(savA, 768, saw5b, 768,
                                                   op, PSTRIDE, 768, 192);
    add_ln_p<4, float, bf16><<<dim3(4096), blk, 0, stream>>>(tgt, op, PSTRIDE, sa_b[5],
                                                             ln_g[0], ln_b[0], t1);

    // ---- cvt pass 2: memory, memory_pos, qp-input = bf16(t1 + tgt_pos2) ----
    {
        CvtJobs C = {};
        C.j[0] = {memory,     nullptr, nullptr, mem_b,    786432};
        C.j[1] = {memory_pos, nullptr, nullptr, mempos_b, 786432};
        C.j[2] = {tgt_pos2,   nullptr, t1,      qpin_b,   393216};
        cvt_multi<<<dim3(288, 3), blk, 0, stream>>>(C);
    }

    // ---- cross attention: q (2 jobs, M=4096) + kv (3 jobs, M=8192) fused
    //      into ONE 1536-block dispatch ----
    {
        JobsM J = {};
        J.j[0] = {tp_b,     wb + 8 * WSTEP, ca_b[0], qc, 0, 32};
        J.j[1] = {qpin_b,   wb + 9 * WSTEP, ca_b[1], qp, 0, 64};
        J.j[2] = {mem_b,    wb + 5 * WSTEP, ca_b[2], kc, 0, 128};
        J.j[3] = {mempos_b, wb + 6 * WSTEP, ca_b[3], kp, 0, 192};
        J.j[4] = {mempos_b, wb + 7 * WSTEP, ca_b[4], vv, 0, 256};
        gemm_multi<<<dim3(6, 256), blk, 0, stream>>>(J, 768, 768, 768, 768);
    }
    attn_scores<<<dim3(8, 4, 48), blk, 0, stream>>>(qc, qp, kc, kp, sc, 512, 1024, SCALE);
    // ---- cvt pass 3: FFN weights into dead qc/qp ----
    {
        CvtJobs C = {};
        C.j[0] = {ff1_w, nullptr, nullptr, ff1b, 196608};
        C.j[1] = {ff2_w, nullptr, nullptr, ff2b, 196608};
        cvt_multi<<<dim3(288, 2), blk, 0, stream>>>(C);
    }
    softmax_mean<4><<<dim3(512, 8), blk, 0, stream>>>(sc, out_att, 512);
    attn_pv_sk<<<dim3(4, 2, 48), blk, 0, stream>>>(sc, vv, pv_ca, PSTRIDE, 512, 1024);
    // fuse: cavA = bf16(pv0 + pv1); caw5b = bf16(ca_w[5])
    {
        CvtJobs C = {};
        C.j[0] = {pv_ca, pv_ca + PSTRIDE, nullptr, cavA,  393216};
        C.j[1] = {ca_w[5], nullptr,       nullptr, caw5b, 73728};
        cvt_multi<<<dim3(288, 2), blk, 0, stream>>>(C);
    }
    // CA out-proj: split-K z=4 (Ks=192), 768 blocks.
    gemm_sk_bb<<<dim3(6, 32, 4), blk, 0, stream>>>(cavA, 768, caw5b, 768,
                                                   op, PSTRIDE, 768, 192);
    add_ln_p<4, bf16, bf16><<<dim3(4096), blk, 0, stream>>>(t1, op, PSTRIDE, ca_b[5],
                                                            ln_g[1], ln_b[1], tca);

    // ---- FFN ----
    {
        JobsM J = {};
        J.j[0] = {tca, ff1b, ff1_b, ffh, 1, 32};
        J.j[1].ycum = BIG; J.j[2].ycum = BIG; J.j[3].ycum = BIG; J.j[4].ycum = BIG;
        gemm_multi<<<dim3(16, 32), blk, 0, stream>>>(J, 768, 768, 2048, 768);
    }
    gemm_sk_bb<<<dim3(6, 32, 4), blk, 0, stream>>>(ffh, 2048, ff2b, 2048,
                                                   fp, PSTRIDE, 768, 512);
    add_ln_p<4, bf16, float><<<dim3(4096), blk, 0, stream>>>(tca, fp, PSTRIDE, ff2_b,
                                                             ln_g[2], ln_b[2], out_t);
}

// Round 12
// 590.238 us; speedup vs baseline: 1.0403x; 1.0311x over previous
//
#include <hip/hip_runtime.h>

// Conditional-DETR decoder layer, MI355X gfx950.
// R17 @ 608.6: CA fusion +16 us (64.3, = 602 TF = m233 2-phase ceiling);
// outproj z=4 REGRESSED ~10 us (6 K-iters -> prologue-dominated + 2x partial
// traffic). Sum-of-dispatches ~420 us vs 608 measured -> ~150-190 us in launch
// gaps/tails across 24 serial dispatches: dispatch-count is the axis.
// R18:
//  1) outprojs revert to split-K z=2 (Ks=384) + add_ln_p<2>.
//  2) add_ln_fuse: SA add_ln emits qpin_b=bf16(t1+tgt_pos2) inline (same
//     post-rounding bf16 -> bit-identical) + absorbs memory/memory_pos cvt
//     as grid-stride tail (dst moved to dead sc_hi; old dst aliased op). -cvt2.
//  3) CA softmax_mean<4> absorbs FFN-weight cvt tail. -cvt3.
// 24 -> 22 dispatches. Predict 608.6 -> ~585; absmax exactly 0.03125.
// R19: unchanged resubmit — R18 bench died on GPU acquisition timeout (infra).

typedef __bf16 bf16;
typedef __attribute__((ext_vector_type(8))) __bf16 bf16x8;
typedef __attribute__((ext_vector_type(4))) float f32x4;

#define D_MODEL 768
#define NH 6
#define HD 128
#define ROWSTRIDE (8 * D_MODEL)  // 6144 (B*D)

#define FENCE() asm volatile("" ::: "memory")

// XCD-aware chunked swizzle: requires gridDim.x*y*z % 8 == 0 (all our grids).
__device__ inline void swz_xyz(int& x, int& y, int& z) {
    const int nx = gridDim.x, ny = gridDim.y;
    const int n = nx * ny * gridDim.z;
    const int flat = blockIdx.x + nx * (blockIdx.y + ny * blockIdx.z);
    const int t = (flat & 7) * (n >> 3) + (flat >> 3);
    x = t % nx;
    const int r = t / nx;
    y = r % ny;
    z = r / ny;
}

// global->LDS direct DMA, 16 B per lane. Dest is wave-uniform base + lane*16.
__device__ __forceinline__ void gld16(const bf16* g, bf16* l) {
    __builtin_amdgcn_global_load_lds(
        (const __attribute__((address_space(1))) unsigned int*)g,
        (__attribute__((address_space(3))) unsigned int*)l, 16, 0, 0);
}

// 8-elem staging loaders -> bf16x8
__device__ inline bf16x8 ld8f(const float* p) {
    f32x4 a = *(const f32x4*)p, b = *(const f32x4*)(p + 4);
    bf16x8 r;
#pragma unroll
    for (int i = 0; i < 4; i++) { r[i] = (bf16)a[i]; r[i + 4] = (bf16)b[i]; }
    return r;
}
__device__ inline bf16x8 ld8bf(const bf16* p, const float* q) {  // bf16 + f32
    bf16x8 x = *(const bf16x8*)p;
    f32x4 a = *(const f32x4*)q, b = *(const f32x4*)(q + 4);
    bf16x8 r;
#pragma unroll
    for (int i = 0; i < 4; i++) { r[i] = (bf16)((float)x[i] + a[i]); r[i + 4] = (bf16)((float)x[i + 4] + b[i]); }
    return r;
}
__device__ inline bf16x8 ld8ff(const float* p, const float* q) {  // f32 + f32
    f32x4 a = *(const f32x4*)p, b = *(const f32x4*)(p + 4);
    f32x4 c = *(const f32x4*)q, d = *(const f32x4*)(q + 4);
    bf16x8 r;
#pragma unroll
    for (int i = 0; i < 4; i++) { r[i] = (bf16)(a[i] + c[i]); r[i + 4] = (bf16)(b[i] + d[i]); }
    return r;
}

// ---------------------------------------------------------------------------
// Multi-segment conversion (grid-stride; blockIdx.y = job).
struct CvtJob { const float* src; const float* src2; const bf16* add; bf16* dst; int nvec; };
struct CvtJobs { CvtJob j[12]; };

__global__ __launch_bounds__(256) void cvt_multi(CvtJobs jobs)
{
    const CvtJob jb = jobs.j[blockIdx.y];
    const int stride = gridDim.x * 256;
    if (jb.src2) {
        for (int i = blockIdx.x * 256 + threadIdx.x; i < jb.nvec; i += stride)
            *(bf16x8*)(jb.dst + (size_t)i * 8) = ld8ff(jb.src + (size_t)i * 8, jb.src2 + (size_t)i * 8);
    } else if (jb.add) {
        for (int i = blockIdx.x * 256 + threadIdx.x; i < jb.nvec; i += stride)
            *(bf16x8*)(jb.dst + (size_t)i * 8) = ld8bf(jb.add + (size_t)i * 8, jb.src + (size_t)i * 8);
    } else {
        for (int i = blockIdx.x * 256 + threadIdx.x; i < jb.nvec; i += stride)
            *(bf16x8*)(jb.dst + (size_t)i * 8) = ld8f(jb.src + (size_t)i * 8);
    }
}

// ---------------------------------------------------------------------------
// All-bf16 multi-job GEMM with per-job y-extents, gload_lds, counted-vmcnt.
struct JobM { const bf16* A; const bf16* W; const float* bias; bf16* C;
              int relu; int ycum; };
struct JobsM { JobM j[5]; };

__global__ __launch_bounds__(256) void gemm_multi(
    JobsM jobs, int lda, int ldw, int ldc, int K)
{
    __shared__ __align__(16) bf16 As[2][128 * 32];
    __shared__ __align__(16) bf16 Bs[2][128 * 32];
    int bx, byg, bzu;
    swz_xyz(bx, byg, bzu);
    int ji = 0;
    while (ji < 4 && byg >= jobs.j[ji].ycum) ji++;
    const JobM jb = jobs.j[ji];
    const int ybase = (ji == 0) ? 0 : jobs.j[ji - 1].ycum;
    const int bm = (byg - ybase) * 128, bn = bx * 128;
    const int tid = threadIdx.x;
    const int wave = tid >> 6, lane = tid & 63;
    const int wm = (wave >> 1) * 64, wn = (wave & 1) * 64;
    const int quad = lane >> 4, m16 = lane & 15;
    const int crow = lane >> 2, ccol = (lane & 3) * 8;
    const bf16* a0 = jb.A + (size_t)(bm + wave * 32 + crow) * lda + ccol;
    const bf16* a1 = a0 + (size_t)16 * lda;
    const bf16* w0 = jb.W + (size_t)(bn + wave * 32 + crow) * ldw + ccol;
    const bf16* w1 = w0 + (size_t)16 * ldw;
    const int wo = wave * 1024;
    f32x4 acc[4][4] = {};
    auto stage = [&](int buf, int k) {
        bf16* dA = As[buf] + wo;
        bf16* dB = Bs[buf] + wo;
        gld16(a0 + k, dA);
        gld16(a1 + k, dA + 512);
        gld16(w0 + k, dB);
        gld16(w1 + k, dB + 512);
    };
    auto compute = [&](int buf) {
        const bf16* rA = As[buf];
        const bf16* rB = Bs[buf];
        bf16x8 af[4], bfr[4];
#pragma unroll
        for (int i = 0; i < 4; i++) {
            af[i]  = *(const bf16x8*)&rA[(wm + i * 16 + m16) * 32 + quad * 8];
            bfr[i] = *(const bf16x8*)&rB[(wn + i * 16 + m16) * 32 + quad * 8];
        }
#pragma unroll
        for (int i = 0; i < 4; i++)
#pragma unroll
            for (int j = 0; j < 4; j++)
                acc[i][j] = __builtin_amdgcn_mfma_f32_16x16x32_bf16(af[i], bfr[j], acc[i][j], 0, 0, 0);
    };
    stage(0, 0);
    stage(1, 32);
    int cur = 0;
    for (int k0 = 0; k0 < K - 32; k0 += 32) {
        asm volatile("s_waitcnt vmcnt(4)" ::: "memory");
        __builtin_amdgcn_s_barrier();
        FENCE();
        compute(cur);
        FENCE();
        __builtin_amdgcn_s_barrier();
        FENCE();
        const int kp2 = k0 + 64;
        if (kp2 < K) stage(cur, kp2);
        cur ^= 1;
    }
    asm volatile("s_waitcnt vmcnt(0)" ::: "memory");
    __builtin_amdgcn_s_barrier();
    FENCE();
    compute(cur);
#pragma unroll
    for (int j = 0; j < 4; j++) {
        const int col = bn + wn + j * 16 + m16;
        const float bv = jb.bias[col];
#pragma unroll
        for (int i = 0; i < 4; i++)
#pragma unroll
            for (int r = 0; r < 4; r++) {
                const int row = bm + wm + i * 16 + quad * 4 + r;
                float val = acc[i][j][r] + bv;
                if (jb.relu) val = fmaxf(val, 0.f);
                jb.C[(size_t)row * ldc + col] = (bf16)val;
            }
    }
}

// ---------------------------------------------------------------------------
// All-bf16 split-K GEMM, counted-vmcnt pipeline, fp32 partials.
__global__ __launch_bounds__(256) void gemm_sk_bb(
    const bf16* __restrict__ A, int lda, const bf16* __restrict__ W, int ldw,
    float* __restrict__ Cp, size_t cstride, int ldc, int Ks)
{
    __shared__ __align__(16) bf16 As[2][128 * 32];
    __shared__ __align__(16) bf16 Bs[2][128 * 32];
    int bx, by, bz;
    swz_xyz(bx, by, bz);
    const int bm = by * 128, bn = bx * 128;
    const int kbase = bz * Ks;
    const int tid = threadIdx.x;
    const int wave = tid >> 6, lane = tid & 63;
    const int wm = (wave >> 1) * 64, wn = (wave & 1) * 64;
    const int quad = lane >> 4, m16 = lane & 15;
    const int crow = lane >> 2, ccol = (lane & 3) * 8;
    const bf16* a0 = A + (size_t)(bm + wave * 32 + crow) * lda + kbase + ccol;
    const bf16* a1 = a0 + (size_t)16 * lda;
    const bf16* w0 = W + (size_t)(bn + wave * 32 + crow) * ldw + kbase + ccol;
    const bf16* w1 = w0 + (size_t)16 * ldw;
    const int wo = wave * 1024;
    f32x4 acc[4][4] = {};
    auto stage = [&](int buf, int k) {
        bf16* dA = As[buf] + wo;
        bf16* dB = Bs[buf] + wo;
        gld16(a0 + k, dA);
        gld16(a1 + k, dA + 512);
        gld16(w0 + k, dB);
        gld16(w1 + k, dB + 512);
    };
    auto compute = [&](int buf) {
        const bf16* rA = As[buf];
        const bf16* rB = Bs[buf];
        bf16x8 af[4], bfr[4];
#pragma unroll
        for (int i = 0; i < 4; i++) {
            af[i]  = *(const bf16x8*)&rA[(wm + i * 16 + m16) * 32 + quad * 8];
            bfr[i] = *(const bf16x8*)&rB[(wn + i * 16 + m16) * 32 + quad * 8];
        }
#pragma unroll
        for (int i = 0; i < 4; i++)
#pragma unroll
            for (int j = 0; j < 4; j++)
                acc[i][j] = __builtin_amdgcn_mfma_f32_16x16x32_bf16(af[i], bfr[j], acc[i][j], 0, 0, 0);
    };
    stage(0, 0);
    stage(1, 32);
    int cur = 0;
    for (int k0 = 0; k0 < Ks - 32; k0 += 32) {
        asm volatile("s_waitcnt vmcnt(4)" ::: "memory");
        __builtin_amdgcn_s_barrier();
        FENCE();
        compute(cur);
        FENCE();
        __builtin_amdgcn_s_barrier();
        FENCE();
        const int kp2 = k0 + 64;
        if (kp2 < Ks) stage(cur, kp2);
        cur ^= 1;
    }
    asm volatile("s_waitcnt vmcnt(0)" ::: "memory");
    __builtin_amdgcn_s_barrier();
    FENCE();
    compute(cur);
    float* out = Cp + (size_t)bz * cstride;
#pragma unroll
    for (int j = 0; j < 4; j++) {
        const int col = bn + wn + j * 16 + m16;
#pragma unroll
        for (int i = 0; i < 4; i++)
#pragma unroll
            for (int r = 0; r < 4; r++) {
                const int row = bm + wm + i * 16 + quad * 4 + r;
                out[(size_t)row * ldc + col] = acc[i][j][r];
            }
    }
}

// ---------------------------------------------------------------------------
// scores[bh,l,s] = scale*(qc.kc + qp.kp), K=256. Counted-vmcnt pipeline.
__global__ __launch_bounds__(256) void attn_scores(
    const bf16* __restrict__ qc, const bf16* __restrict__ qp,
    const bf16* __restrict__ kc, const bf16* __restrict__ kp,
    bf16* __restrict__ scores, int Lq, int S, float scale)
{
    __shared__ __align__(16) bf16 As[2][128 * 32];
    __shared__ __align__(16) bf16 Bs[2][128 * 32];
    int bx, by, bz;
    swz_xyz(bx, by, bz);
    const int bh = bz;
    const int b = bh / NH, h = bh % NH;
    const int bm = by * 128, bn = bx * 128;
    const int tid = threadIdx.x;
    const int wave = tid >> 6, lane = tid & 63;
    const int wm = (wave >> 1) * 64, wn = (wave & 1) * 64;
    const int quad = lane >> 4, m16 = lane & 15;
    const int crow = lane >> 2, ccol = (lane & 3) * 8;
    const size_t hb = (size_t)b * D_MODEL + h * HD;
    const size_t ar0 = (size_t)(bm + wave * 32 + crow) * ROWSTRIDE + hb + ccol;
    const size_t ar1 = ar0 + (size_t)16 * ROWSTRIDE;
    const size_t br0 = (size_t)(bn + wave * 32 + crow) * ROWSTRIDE + hb + ccol;
    const size_t br1 = br0 + (size_t)16 * ROWSTRIDE;
    const int wo = wave * 1024;
    f32x4 acc[4][4] = {};
    auto stage = [&](int buf, int k) {
        const bf16* qsrc = (k < 128) ? qc : qp;
        const bf16* ksrc = (k < 128) ? kc : kp;
        const int kcol = k & 127;
        bf16* dA = As[buf] + wo;
        bf16* dB = Bs[buf] + wo;
        gld16(qsrc + ar0 + kcol, dA);
        gld16(qsrc + ar1 + kcol, dA + 512);
        gld16(ksrc + br0 + kcol, dB);
        gld16(ksrc + br1 + kcol, dB + 512);
    };
    auto compute = [&](int buf) {
        const bf16* rA = As[buf];
        const bf16* rB = Bs[buf];
        bf16x8 af[4], bfr[4];
#pragma unroll
        for (int i = 0; i < 4; i++) {
            af[i]  = *(const bf16x8*)&rA[(wm + i * 16 + m16) * 32 + quad * 8];
            bfr[i] = *(const bf16x8*)&rB[(wn + i * 16 + m16) * 32 + quad * 8];
        }
#pragma unroll
        for (int i = 0; i < 4; i++)
#pragma unroll
            for (int j = 0; j < 4; j++)
                acc[i][j] = __builtin_amdgcn_mfma_f32_16x16x32_bf16(af[i], bfr[j], acc[i][j], 0, 0, 0);
    };
    stage(0, 0);
    stage(1, 32);
    int cur = 0;
    for (int k0 = 0; k0 < 224; k0 += 32) {
        asm volatile("s_waitcnt vmcnt(4)" ::: "memory");
        __builtin_amdgcn_s_barrier();
        FENCE();
        compute(cur);
        FENCE();
        __builtin_amdgcn_s_barrier();
        FENCE();
        const int kp2 = k0 + 64;
        if (kp2 < 256) stage(cur, kp2);
        cur ^= 1;
    }
    asm volatile("s_waitcnt vmcnt(0)" ::: "memory");
    __builtin_amdgcn_s_barrier();
    FENCE();
    compute(cur);
    bf16* sb = scores + (size_t)bh * Lq * S;
#pragma unroll
    for (int i = 0; i < 4; i++)
#pragma unroll
        for (int j = 0; j < 4; j++)
#pragma unroll
            for (int r = 0; r < 4; r++)
                sb[(size_t)(bm + wm + i * 16 + quad * 4 + r) * S + bn + wn + j * 16 + m16]
                    = (bf16)(acc[i][j][r] * scale);
}

// ---------------------------------------------------------------------------
// Fused softmax + head-mean. One block per (b,l): all NH=6 head rows.
// Optional appended cvt tail (cw1->cd1, cw2->cd2; n in vec8 units).
template <int N>
__global__ __launch_bounds__(256) void softmax_mean(
    bf16* __restrict__ scores, float* __restrict__ att, int Lq,
    const float* cw1, bf16* cd1, int n1, const float* cw2, bf16* cd2, int n2)
{
    const int S = N << 8;
    const int l = blockIdx.x, b = blockIdx.y;
    const int tid = threadIdx.x;
    __shared__ float red[4], red2[4];
    float macc[N];
#pragma unroll
    for (int i = 0; i < N; i++) macc[i] = 0.f;
    for (int h = 0; h < NH; h++) {
        bf16* p = scores + ((size_t)(b * NH + h) * Lq + l) * S;
        float vals[N];
        float mx = -1e30f;
#pragma unroll
        for (int i = 0; i < N; i++) { vals[i] = (float)p[tid + (i << 8)]; mx = fmaxf(mx, vals[i]); }
        for (int off = 32; off; off >>= 1) mx = fmaxf(mx, __shfl_xor(mx, off, 64));
        if ((tid & 63) == 0) red[tid >> 6] = mx;
        __syncthreads();
        mx = fmaxf(fmaxf(red[0], red[1]), fmaxf(red[2], red[3]));
        float sum = 0.f;
#pragma unroll
        for (int i = 0; i < N; i++) { vals[i] = __expf(vals[i] - mx); sum += vals[i]; }
        for (int off = 32; off; off >>= 1) sum += __shfl_xor(sum, off, 64);
        if ((tid & 63) == 0) red2[tid >> 6] = sum;
        __syncthreads();
        const float inv = 1.f / (red2[0] + red2[1] + red2[2] + red2[3]);
#pragma unroll
        for (int i = 0; i < N; i++) {
            const float w = vals[i] * inv;
            p[tid + (i << 8)] = (bf16)w;
            macc[i] += w;
        }
    }
    float* ao = att + ((size_t)b * Lq + l) * S;
#pragma unroll
    for (int i = 0; i < N; i++) ao[tid + (i << 8)] = macc[i] * (1.f / 6.f);
    // appended cvt tail
    if (cw1) {
        const int gid = (blockIdx.y * gridDim.x + blockIdx.x) * 256 + tid;
        if (gid < n1) *(bf16x8*)(cd1 + (size_t)gid * 8) = ld8f(cw1 + (size_t)gid * 8);
        if (gid < n2) *(bf16x8*)(cd2 + (size_t)gid * 8) = ld8f(cw2 + (size_t)gid * 8);
    }
}

// ---------------------------------------------------------------------------
// Split-S PV. A-side (softmax weights) via gload_lds; V transposed reg-scatter.
__global__ __launch_bounds__(256) void attn_pv_sk(
    const bf16* __restrict__ wsm, const bf16* __restrict__ v,
    float* __restrict__ Pv, size_t pstride, int Lq, int S)
{
    __shared__ __align__(16) bf16 As[128 * 32];
    __shared__ __align__(16) bf16 BsT[128][40];
    int bx, by, bz;
    swz_xyz(bx, by, bz);
    const int bh = bz;
    const int b = bh / NH, h = bh % NH;
    const int bm = bx * 128;
    const int kbase = by * (S >> 1);
    const int tid = threadIdx.x;
    const int wave = tid >> 6, lane = tid & 63;
    const int wm = (wave >> 1) * 64, wn = (wave & 1) * 64;
    const int quad = lane >> 4, m16 = lane & 15;
    const int crow = lane >> 2, ccol = (lane & 3) * 8;
    const int kk0 = tid >> 4, e0 = (tid & 15) * 8;
    f32x4 acc[4][4] = {};
    const bf16* wbase = wsm + (size_t)(bh * Lq + bm) * S + kbase;
    const size_t vb = (size_t)b * D_MODEL + h * HD;
    const bf16* a0 = wbase + (size_t)(wave * 32 + crow) * S + ccol;
    const bf16* a1 = a0 + (size_t)16 * S;
    bf16* lA = As + wave * 1024;
    bf16x8 v0, v1;
    v0 = *(const bf16x8*)(v + (size_t)(kbase + kk0) * ROWSTRIDE + vb + e0);
    v1 = *(const bf16x8*)(v + (size_t)(kbase + kk0 + 16) * ROWSTRIDE + vb + e0);
    for (int k0 = 0; k0 < (S >> 1); k0 += 32) {
        gld16(a0 + k0, lA);
        gld16(a1 + k0, lA + 512);
#pragma unroll
        for (int i = 0; i < 8; i++) { BsT[e0 + i][kk0] = v0[i]; BsT[e0 + i][kk0 + 16] = v1[i]; }
        __syncthreads();
        const int kn = k0 + 32;
        if (kn < (S >> 1)) {
            v0 = *(const bf16x8*)(v + (size_t)(kbase + kn + kk0) * ROWSTRIDE + vb + e0);
            v1 = *(const bf16x8*)(v + (size_t)(kbase + kn + kk0 + 16) * ROWSTRIDE + vb + e0);
        }
        bf16x8 af[4], bfr[4];
#pragma unroll
        for (int i = 0; i < 4; i++) {
            af[i]  = *(const bf16x8*)&As[(wm + i * 16 + m16) * 32 + quad * 8];
            bfr[i] = *(const bf16x8*)&BsT[wn + i * 16 + m16][quad * 8];
        }
#pragma unroll
        for (int i = 0; i < 4; i++)
#pragma unroll
            for (int j = 0; j < 4; j++)
                acc[i][j] = __builtin_amdgcn_mfma_f32_16x16x32_bf16(af[i], bfr[j], acc[i][j], 0, 0, 0);
        __syncthreads();
    }
    float* out = Pv + by * pstride;
#pragma unroll
    for (int i = 0; i < 4; i++)
#pragma unroll
        for (int j = 0; j < 4; j++)
#pragma unroll
            for (int r = 0; r < 4; r++)
                out[(size_t)(bm + wm + i * 16 + quad * 4 + r) * ROWSTRIDE + vb + wn + j * 16 + m16]
                    = acc[i][j][r];
}

// ---------------------------------------------------------------------------
// out = LN(resid + sum_{p<NP} P[p] + xbias) * g + be.
template <int NP, typename TR, typename TO>
__global__ __launch_bounds__(256) void add_ln_p(
    const TR* __restrict__ resid, const float* __restrict__ P, size_t pstride,
    const float* __restrict__ xbias,
    const float* __restrict__ g, const float* __restrict__ be, TO* __restrict__ out)
{
    const size_t base = (size_t)blockIdx.x * D_MODEL;
    const int tid = threadIdx.x;
    float v[3];
#pragma unroll
    for (int i = 0; i < 3; i++) {
        const int c = tid + (i << 8);
        float x = xbias[c];
#pragma unroll
        for (int p = 0; p < NP; p++) x += P[p * pstride + base + c];
        v[i] = (float)resid[base + c] + x;
    }
    float s = v[0] + v[1] + v[2];
    float s2 = v[0] * v[0] + v[1] * v[1] + v[2] * v[2];
    for (int off = 32; off; off >>= 1) { s += __shfl_xor(s, off, 64); s2 += __shfl_xor(s2, off, 64); }
    __shared__ float rs[4], rs2[4];
    if ((tid & 63) == 0) { rs[tid >> 6] = s; rs2[tid >> 6] = s2; }
    __syncthreads();
    s = rs[0] + rs[1] + rs[2] + rs[3];
    s2 = rs2[0] + rs2[1] + rs2[2] + rs2[3];
    const float mean = s * (1.f / 768.f);
    const float var = s2 * (1.f / 768.f) - mean * mean;
    const float inv = rsqrtf(var + 1e-5f);
#pragma unroll
    for (int i = 0; i < 3; i++) {
        const int c = tid + (i << 8);
        out[base + c] = (TO)((v[i] - mean) * inv * g[c] + be[c]);
    }
}

// ---------------------------------------------------------------------------
// SA add_ln with fused qpin emit + memory cvt tail.
// t1 = LN(tgt + P0 + P1 + xbias); qpin = bf16((float)t1 + tp2);
// tail: mem_b = bf16(memory), mempos_b = bf16(memory_pos), nmem vec8 each.
__global__ __launch_bounds__(256) void add_ln_fuse(
    const float* __restrict__ resid, const float* __restrict__ P, size_t pstride,
    const float* __restrict__ xbias,
    const float* __restrict__ g, const float* __restrict__ be,
    bf16* __restrict__ out, const float* __restrict__ tp2, bf16* __restrict__ qpin,
    const float* __restrict__ mem, bf16* __restrict__ memb,
    const float* __restrict__ mempos, bf16* __restrict__ memposb, int nmem)
{
    const size_t base = (size_t)blockIdx.x * D_MODEL;
    const int tid = threadIdx.x;
    float v[3];
#pragma unroll
    for (int i = 0; i < 3; i++) {
        const int c = tid + (i << 8);
        float x = xbias[c] + P[base + c] + P[pstride + base + c];
        v[i] = resid[base + c] + x;
    }
    float s = v[0] + v[1] + v[2];
    float s2 = v[0] * v[0] + v[1] * v[1] + v[2] * v[2];
    for (int off = 32; off; off >>= 1) { s += __shfl_xor(s, off, 64); s2 += __shfl_xor(s2, off, 64); }
    __shared__ float rs[4], rs2[4];
    if ((tid & 63) == 0) { rs[tid >> 6] = s; rs2[tid >> 6] = s2; }
    __syncthreads();
    s = rs[0] + rs[1] + rs[2] + rs[3];
    s2 = rs2[0] + rs2[1] + rs2[2] + rs2[3];
    const float mean = s * (1.f / 768.f);
    const float var = s2 * (1.f / 768.f) - mean * mean;
    const float inv = rsqrtf(var + 1e-5f);
#pragma unroll
    for (int i = 0; i < 3; i++) {
        const int c = tid + (i << 8);
        const bf16 o = (bf16)((v[i] - mean) * inv * g[c] + be[c]);
        out[base + c] = o;
        qpin[base + c] = (bf16)((float)o + tp2[base + c]);
    }
    // tail: memory / memory_pos -> bf16 (grid-stride, 1M threads cover nmem)
    const int gid = blockIdx.x * 256 + tid;
    if (gid < nmem) {
        *(bf16x8*)(memb + (size_t)gid * 8) = ld8f(mem + (size_t)gid * 8);
        *(bf16x8*)(memposb + (size_t)gid * 8) = ld8f(mempos + (size_t)gid * 8);
    }
}

// ---------------------------------------------------------------------------
extern "C" void kernel_launch(void* const* d_in, const int* in_sizes, int n_in,
                              void* d_out, int out_size, void* d_ws, size_t ws_size,
                              hipStream_t stream)
{
    const float* tgt        = (const float*)d_in[0];
    const float* memory     = (const float*)d_in[1];
    const float* tgt_pos    = (const float*)d_in[2];
    const float* memory_pos = (const float*)d_in[3];
    const float* tgt_pos2   = (const float*)d_in[4];
    const float *sa_w[6], *sa_b[6], *ca_w[6], *ca_b[6];
    for (int i = 0; i < 6; i++) {
        sa_w[i] = (const float*)d_in[5 + 2 * i];  sa_b[i] = (const float*)d_in[6 + 2 * i];
        ca_w[i] = (const float*)d_in[17 + 2 * i]; ca_b[i] = (const float*)d_in[18 + 2 * i];
    }
    const float* ff1_w = (const float*)d_in[29]; const float* ff1_b = (const float*)d_in[30];
    const float* ff2_w = (const float*)d_in[31]; const float* ff2_b = (const float*)d_in[32];
    const float* ln_g[3] = {(const float*)d_in[33], (const float*)d_in[35], (const float*)d_in[37]};
    const float* ln_b[3] = {(const float*)d_in[34], (const float*)d_in[36], (const float*)d_in[38]};

    // ---- workspace (106,954,752 B) ----
    char* ws = (char*)d_ws;
    bf16* qc  = (bf16*)(ws);                // [0, 6291456)
    bf16* qp  = (bf16*)(ws + 6291456);      // [6291456, 12582912)
    bf16* kc  = (bf16*)(ws + 12582912);     // [12582912, 25165824)
    bf16* kp  = (bf16*)(ws + 25165824);     // [25165824, 37748736)
    bf16* vv  = (bf16*)(ws + 37748736);     // [37748736, 50331648)
    bf16* t1  = (bf16*)(ws + 50331648);     // [50331648, 56623104)
    bf16* sc  = (bf16*)(ws + 56623104);     // [56623104, 106954752) 50.33 MB
    const size_t PSTRIDE = 3145728;  // floats per 12.58 MB slice
    float* pv_sa = (float*)(ws + 81788928);  // sc_hi: SA PV pair (sc_lo = SA scores live)
    float* pv_ca = (float*)(ws + 12582912);  // kc+kp: dead after CA scores
    float* op    = (float*)(ws + 56623104);  // sc_lo: out-proj pair (z=2)
    float* fp    = (float*)(ws + 56623104);  // FFN2 4-slice = full sc (dead)
    bf16*  tca   = kc;                       // Pv_ca dead after CA out-proj
    bf16*  ffh   = kp;                       // 16.78 MB over dead kp+vv

    // bf16 staging (liveness-checked):
    //  - tgt_b in sc_lo: live only during SA proj.
    //  - mem_b/mempos_b in sc_hi (ws+81.8MB; pv_sa dead after savA cvt;
    //    add_ln_fuse reads op = sc_lo only — disjoint); consumed by CA kv
    //    proj before CA scores overwrite sc.
    bf16* tgt_b    = sc;
    bf16* mem_b    = (bf16*)(ws + 81788928);
    bf16* mempos_b = mem_b + 6291456;
    bf16* wb       = (bf16*)d_out;
    const size_t WSTEP = 589824;  // 768*768
    bf16* tp_b   = (bf16*)((char*)d_out + 12582912);
    bf16* qpin_b = tp_b + 3145728;
    bf16* ff1b   = qc;
    bf16* ff2b   = qp;
    bf16* savA   = kc;                      // 6.29 MB
    bf16* saw5b  = kc + 3145728;            // +1.18 MB
    bf16* cavA   = vv;                      // 6.29 MB
    bf16* caw5b  = vv + 3145728;            // +1.18 MB

    float* out_t    = (float*)d_out;        // (L,B,D)
    float* out_att  = out_t + 3145728;      // (B,L,S)
    float* out_satt = out_att + 4194304;    // (B,L,L)

    const dim3 blk(256);
    const float SCALE = 0.0625f;
    const int BIG = 0x7fffffff;

    // ---- cvt pass 1: 10 weights + tgt + tgt_pos(persistent) ----
    {
        CvtJobs C = {};
        for (int i = 0; i < 5; i++) C.j[i] = {sa_w[i], nullptr, nullptr, wb + i * WSTEP, 73728};
        for (int i = 0; i < 3; i++) C.j[5 + i] = {ca_w[2 + i], nullptr, nullptr, wb + (5 + i) * WSTEP, 73728};
        C.j[8]  = {ca_w[0], nullptr, nullptr, wb + 8 * WSTEP, 73728};
        C.j[9]  = {ca_w[1], nullptr, nullptr, wb + 9 * WSTEP, 73728};
        C.j[10] = {tgt,     nullptr, nullptr, tgt_b, 393216};
        C.j[11] = {tgt_pos, nullptr, nullptr, tp_b,  393216};
        cvt_multi<<<dim3(288, 12), blk, 0, stream>>>(C);
    }

    // ---- self attention: 5 projections, one dispatch (960 blocks) ----
    {
        JobsM J = {};
        J.j[0] = {tp_b,  wb + 0 * WSTEP, sa_b[0], qc, 0, 32};
        J.j[1] = {tgt_b, wb + 1 * WSTEP, sa_b[1], qp, 0, 64};
        J.j[2] = {tp_b,  wb + 2 * WSTEP, sa_b[2], kc, 0, 96};
        J.j[3] = {tgt_b, wb + 3 * WSTEP, sa_b[3], kp, 0, 128};
        J.j[4] = {tgt_b, wb + 4 * WSTEP, sa_b[4], vv, 0, 160};
        gemm_multi<<<dim3(6, 160), blk, 0, stream>>>(J, 768, 768, 768, 768);
    }
    attn_scores<<<dim3(4, 4, 48), blk, 0, stream>>>(qc, qp, kc, kp, sc, 512, 512, SCALE);
    softmax_mean<2><<<dim3(512, 8), blk, 0, stream>>>(sc, out_satt, 512,
                                                      nullptr, nullptr, 0, nullptr, nullptr, 0);
    attn_pv_sk<<<dim3(4, 2, 48), blk, 0, stream>>>(sc, vv, pv_sa, PSTRIDE, 512, 512);
    // fuse: savA = bf16(pv0 + pv1); saw5b = bf16(sa_w[5])
    {
        CvtJobs C = {};
        C.j[0] = {pv_sa, pv_sa + PSTRIDE, nullptr, savA,  393216};
        C.j[1] = {sa_w[5], nullptr,       nullptr, saw5b, 73728};
        cvt_multi<<<dim3(288, 2), blk, 0, stream>>>(C);
    }
    // SA out-proj: split-K z=2 (Ks=384).
    gemm_sk_bb<<<dim3(6, 32, 2), blk, 0, stream>>>(savA, 768, saw5b, 768,
                                                   op, PSTRIDE, 768, 384);
    // add_ln + qpin emit + memory cvt tail  [replaces add_ln1 + cvt2]
    add_ln_fuse<<<dim3(4096), blk, 0, stream>>>(tgt, op, PSTRIDE, sa_b[5],
                                                ln_g[0], ln_b[0], t1,
                                                tgt_pos2, qpin_b,
                                                memory, mem_b, memory_pos, mempos_b, 786432);

    // ---- cross attention: q + kv fused into ONE 1536-block dispatch ----
    {
        JobsM J = {};
        J.j[0] = {tp_b,     wb + 8 * WSTEP, ca_b[0], qc, 0, 32};
        J.j[1] = {qpin_b,   wb + 9 * WSTEP, ca_b[1], qp, 0, 64};
        J.j[2] = {mem_b,    wb + 5 * WSTEP, ca_b[2], kc, 0, 128};
        J.j[3] = {mempos_b, wb + 6 * WSTEP, ca_b[3], kp, 0, 192};
        J.j[4] = {mempos_b, wb + 7 * WSTEP, ca_b[4], vv, 0, 256};
        gemm_multi<<<dim3(6, 256), blk, 0, stream>>>(J, 768, 768, 768, 768);
    }
    attn_scores<<<dim3(8, 4, 48), blk, 0, stream>>>(qc, qp, kc, kp, sc, 512, 1024, SCALE);
    // CA softmax + head-mean + FFN-weight cvt tail  [replaces softmax + cvt3]
    softmax_mean<4><<<dim3(512, 8), blk, 0, stream>>>(sc, out_att, 512,
                                                      ff1_w, ff1b, 196608,
                                                      ff2_w, ff2b, 196608);
    attn_pv_sk<<<dim3(4, 2, 48), blk, 0, stream>>>(sc, vv, pv_ca, PSTRIDE, 512, 1024);
    // fuse: cavA = bf16(pv0 + pv1); caw5b = bf16(ca_w[5])
    {
        CvtJobs C = {};
        C.j[0] = {pv_ca, pv_ca + PSTRIDE, nullptr, cavA,  393216};
        C.j[1] = {ca_w[5], nullptr,       nullptr, caw5b, 73728};
        cvt_multi<<<dim3(288, 2), blk, 0, stream>>>(C);
    }
    // CA out-proj: split-K z=2 (Ks=384).
    gemm_sk_bb<<<dim3(6, 32, 2), blk, 0, stream>>>(cavA, 768, caw5b, 768,
                                                   op, PSTRIDE, 768, 384);
    add_ln_p<2, bf16, bf16><<<dim3(4096), blk, 0, stream>>>(t1, op, PSTRIDE, ca_b[5],
                                                            ln_g[1], ln_b[1], tca);

    // ---- FFN ----
    {
        JobsM J = {};
        J.j[0] = {tca, ff1b, ff1_b, ffh, 1, 32};
        J.j[1].ycum = BIG; J.j[2].ycum = BIG; J.j[3].ycum = BIG; J.j[4].ycum = BIG;
        gemm_multi<<<dim3(16, 32), blk, 0, stream>>>(J, 768, 768, 2048, 768);
    }
    gemm_sk_bb<<<dim3(6, 32, 4), blk, 0, stream>>>(ffh, 2048, ff2b, 2048,
                                                   fp, PSTRIDE, 768, 512);
    add_ln_p<4, bf16, float><<<dim3(4096), blk, 0, stream>>>(tca, fp, PSTRIDE, ff2_b,
                                                             ln_g[2], ln_b[2], out_t);
}